// Round 1
// baseline (3027.300 us; speedup 1.0000x reference)
//
#include <hip/hip_runtime.h>

// ---------- types / helpers ----------
typedef unsigned short u16;
typedef short  s16x8 __attribute__((ext_vector_type(8)));
typedef float  f32x4 __attribute__((ext_vector_type(4)));
typedef unsigned short u16x4 __attribute__((ext_vector_type(4)));

#define LDS_AS __attribute__((address_space(3)))
#define GLB_AS __attribute__((address_space(1)))

__device__ __forceinline__ float bf2f(u16 x) {
    unsigned u = ((unsigned)x) << 16;
    return __builtin_bit_cast(float, u);
}
__device__ __forceinline__ u16 f2bf(float f) {
    unsigned u = __builtin_bit_cast(unsigned, f);
    return (u16)((u + 0x7FFFu + ((u >> 16) & 1u)) >> 16);  // RNE
}
__device__ __forceinline__ void gload16(const u16* g, u16* l) {
    __builtin_amdgcn_global_load_lds((const GLB_AS unsigned int*)g,
                                     (LDS_AS unsigned int*)l, 16, 0, 0);
}

static constexpr int Lc = 4, Sc = 2048, Dc = 1024, Hc = 2048, Mc = 8192;
static constexpr int CH = 64, CL = 32;  // scan chunks / chunk length (CH*CL == Sc)
static constexpr int NCHAN = 4 * Hc;    // B*H = 8192 channels

// ============================================================================
// 256x256 8-phase GEMM (T2+T3+T4+T5): C[M,N] = A[M,K] @ Bw[N,K]^T + bias
// BK=64, 512 threads (2Mx4N waves), 128KiB LDS double-buffer, XOR-swizzled
// LDS ( byte ^= (row&7)<<4 , applied as pre-swizzled global source + swizzled
// ds_read ), raw s_barrier + counted vmcnt(6) (never drains in main loop).
// CONV=1: logical K=3*H over A[M,H] with row shift seg-1 and zero padding.
// ============================================================================
#define BAR() __builtin_amdgcn_s_barrier()
#define VMCNT(n) asm volatile("s_waitcnt vmcnt(" #n ")" ::: "memory")

#define READ_A(d, BUF, MH)                                                     \
    _Pragma("unroll") for (int mf = 0; mf < 4; ++mf) {                         \
        d[mf][0] = *(const s16x8*)(aB0 + (BUF)*16384 + (MH)*4096 + mf*1024);   \
        d[mf][1] = *(const s16x8*)(aB1 + (BUF)*16384 + (MH)*4096 + mf*1024);   \
    }
#define READ_B(BUF, NH)                                                        \
    _Pragma("unroll") for (int jb = 0; jb < 2; ++jb) {                         \
        bq[jb][0] = *(const s16x8*)(bB0 + (BUF)*16384 + (NH)*2048 + jb*1024);  \
        bq[jb][1] = *(const s16x8*)(bB1 + (BUF)*16384 + (NH)*2048 + jb*1024);  \
    }
#define QUAD(a, MH, NH)                                                        \
    _Pragma("unroll") for (int mf = 0; mf < 4; ++mf)                           \
    _Pragma("unroll") for (int jb = 0; jb < 2; ++jb)                           \
    _Pragma("unroll") for (int kk = 0; kk < 2; ++kk)                           \
        acc[(MH)*4 + mf][(NH)*2 + jb] = __builtin_amdgcn_mfma_f32_16x16x32_bf16( \
            a[mf][kk], bq[jb][kk], acc[(MH)*4 + mf][(NH)*2 + jb], 0, 0, 0);

#define STAGE_A(BUF, H, KT) {                                                  \
    if (CONV) {                                                                \
        const int seg_ = ((KT)*64) >> 11;                                      \
        const int kb_  = ((KT)*64) & (Hc - 1);                                 \
        const int r0_  = convRow + (H)*128 + seg_;                             \
        const u16* s0_ = ((unsigned)(r0_ - bb) < (unsigned)Sc)                 \
                             ? A + (size_t)r0_ * lda + kb_ + scol : zerobuf;   \
        const u16* s1_ = ((unsigned)(r0_ + 8 - bb) < (unsigned)Sc)             \
                             ? A + (size_t)(r0_ + 8) * lda + kb_ + scol : zerobuf; \
        gload16(s0_, ldsA + (BUF)*16384 + (H)*8192);                           \
        gload16(s1_, ldsA + (BUF)*16384 + (H)*8192 + 512);                     \
    } else {                                                                   \
        const u16* s_ = srcA + (size_t)((H)*128) * lda + (KT)*64;              \
        gload16(s_,                   ldsA + (BUF)*16384 + (H)*8192);          \
        gload16(s_ + 8*(size_t)lda,   ldsA + (BUF)*16384 + (H)*8192 + 512);    \
    } }
#define STAGE_B(BUF, H, KT) {                                                  \
    const u16* s_ = srcB + (size_t)((H)*128) * K + (KT)*64;                    \
    gload16(s_,                 ldsB + (BUF)*16384 + (H)*8192);                \
    gload16(s_ + 8*(size_t)K,   ldsB + (BUF)*16384 + (H)*8192 + 512);          \
}

template <int CONV>
__global__ __launch_bounds__(512, 2)
void gemm8(const u16* __restrict__ A, const u16* __restrict__ Bw,
           const float* __restrict__ bias, u16* __restrict__ Cb,
           int M, int N, int K, int lda, const u16* __restrict__ zerobuf) {
    (void)M;
    __shared__ __align__(16) u16 As[2][256][64];   // 64 KiB
    __shared__ __align__(16) u16 Bs[2][256][64];   // 64 KiB

    const int tid = threadIdx.x;
    const int w = tid >> 6, l = tid & 63;
    const int wm = w & 1, wn = w >> 1;           // 2 x 4 wave grid
    const int rowBase = blockIdx.y * 256;
    const int colBase = blockIdx.x * 256;

    // ---- staging (pre-swizzled source; LDS dest is linear) ----
    const int srow = w * 16 + (l >> 3);          // row within 128-row half
    const int scol = ((l & 7) ^ (l >> 3)) << 3;  // pre-swizzled element col
    const u16* srcB = Bw + (size_t)(colBase + srow) * K + scol;
    const u16* srcA = A + (size_t)(rowBase + srow) * lda + scol;   // non-conv
    u16* const ldsA = &As[0][0][0] + w * 1024;   // + BUF*16384 + H*8192 + j*512
    u16* const ldsB = &Bs[0][0][0] + w * 1024;
    const int bb = rowBase & ~(Sc - 1);          // batch start (conv)
    const int convRow = rowBase + srow - 1;      // + H*128 + seg

    // ---- fragment read bases (swizzled ds_read addresses) ----
    const int r16 = l & 15, slot = l >> 4;
    const int swz = (r16 & 7) << 4;                      // byte swizzle
    const int co0 = (((slot << 4)      ) ^ swz) >> 1;    // u16 units, kk=0
    const int co1 = (((slot << 4) | 64 ) ^ swz) >> 1;    // kk=1
    const u16* aB0 = &As[0][0][0] + (wm * 128 + r16) * 64 + co0;
    const u16* aB1 = &As[0][0][0] + (wm * 128 + r16) * 64 + co1;
    const u16* bB0 = &Bs[0][0][0] + (wn * 64  + r16) * 64 + co0;
    const u16* bB1 = &Bs[0][0][0] + (wn * 64  + r16) * 64 + co1;

    f32x4 acc[8][4];
#pragma unroll
    for (int m = 0; m < 8; ++m)
#pragma unroll
        for (int n = 0; n < 4; ++n)
#pragma unroll
            for (int r = 0; r < 4; ++r) acc[m][n][r] = 0.f;

    s16x8 a0[4][2], a1[4][2], bq[2][2];

    // ---- prologue: tile0 complete + tile1 {A0,A1,B0}; 3 half-tiles in flight
    STAGE_A(0, 0, 0); STAGE_A(0, 1, 0); STAGE_B(0, 0, 0); STAGE_B(0, 1, 0);
    VMCNT(4);
    STAGE_A(1, 0, 1); STAGE_A(1, 1, 1); STAGE_B(1, 0, 1);
    VMCNT(6);
    BAR();

    const int NI = K >> 7;                  // 2 K-tiles per iteration
    for (int i = 0; i < NI; ++i) {
        const int t1 = 2 * i + 1, t2 = 2 * i + 2, t3 = 2 * i + 3;
        const bool more = (i + 1 < NI);
        // -- phase 1: tile even (buf0), quad (0,0); stage t1.B1 -> buf1
        READ_A(a0, 0, 0); READ_B(0, 0);
        STAGE_B(1, 1, t1);
        BAR();
        __builtin_amdgcn_s_setprio(1); QUAD(a0, 0, 0); __builtin_amdgcn_s_setprio(0);
        BAR();
        // -- phase 2: quad (1,0)
        READ_A(a1, 0, 1);
        BAR();
        __builtin_amdgcn_s_setprio(1); QUAD(a1, 1, 0); __builtin_amdgcn_s_setprio(0);
        BAR();
        // -- phase 3: quad (0,1); stage t2.A0,t2.A1 -> buf0 (A fully read)
        READ_B(0, 1);
        if (more) { STAGE_A(0, 0, t2); STAGE_A(0, 1, t2); }
        BAR();
        __builtin_amdgcn_s_setprio(1); QUAD(a0, 0, 1); __builtin_amdgcn_s_setprio(0);
        BAR();
        // -- phase 4: quad (1,1); stage t2.B0; tile-boundary counted wait
        if (more) STAGE_B(0, 0, t2);
        BAR();
        __builtin_amdgcn_s_setprio(1); QUAD(a1, 1, 1); __builtin_amdgcn_s_setprio(0);
        if (more) { VMCNT(6); } else { VMCNT(0); }
        BAR();
        // -- phase 5: tile odd (buf1), quad (0,0); stage t2.B1
        READ_A(a0, 1, 0); READ_B(1, 0);
        if (more) STAGE_B(0, 1, t2);
        BAR();
        __builtin_amdgcn_s_setprio(1); QUAD(a0, 0, 0); __builtin_amdgcn_s_setprio(0);
        BAR();
        // -- phase 6: quad (1,0)
        READ_A(a1, 1, 1);
        BAR();
        __builtin_amdgcn_s_setprio(1); QUAD(a1, 1, 0); __builtin_amdgcn_s_setprio(0);
        BAR();
        // -- phase 7: quad (0,1); stage t3.A0,t3.A1 -> buf1
        READ_B(1, 1);
        if (more) { STAGE_A(1, 0, t3); STAGE_A(1, 1, t3); }
        BAR();
        __builtin_amdgcn_s_setprio(1); QUAD(a0, 0, 1); __builtin_amdgcn_s_setprio(0);
        BAR();
        // -- phase 8: quad (1,1); stage t3.B0; counted wait for next iter
        if (more) STAGE_B(1, 0, t3);
        BAR();
        __builtin_amdgcn_s_setprio(1); QUAD(a1, 1, 1); __builtin_amdgcn_s_setprio(0);
        if (more) VMCNT(6);
        BAR();
    }

    // ---- epilogue ----
    const int coll  = colBase + wn * 64 + r16;
    const int row00 = rowBase + wm * 128 + slot * 4;
#pragma unroll
    for (int m8 = 0; m8 < 8; ++m8) {
#pragma unroll
        for (int n4 = 0; n4 < 4; ++n4) {
            const int col = coll + n4 * 16;
            const float bv = bias[col];
            const int row0 = row00 + m8 * 16;
#pragma unroll
            for (int r = 0; r < 4; ++r)
                Cb[(size_t)(row0 + r) * N + col] = f2bf(acc[m8][n4][r] + bv);
        }
    }
}

// ---------- legacy 128x128 GEMM (kept for down-proj EPI path) ----------
template <int CONV, int EPI>
__global__ __launch_bounds__(256)
void gemm_bt(const u16* __restrict__ A, const u16* __restrict__ Bw,
             const float* __restrict__ bias,
             u16* __restrict__ Cb, float* __restrict__ Cf,
             const float* __restrict__ resid, u16* __restrict__ xout,
             int M, int N, int K, int lda, const u16* __restrict__ zerobuf) {
    __shared__ __align__(16) u16 As[128 * 32];
    __shared__ __align__(16) u16 Bs[128 * 32];
    const int tid  = threadIdx.x;
    const int wave = tid >> 6, lane = tid & 63;
    const int rowBase = blockIdx.y * 128;
    const int colBase = blockIdx.x * 128;
    const int srow = tid >> 2;          // staging row within 0..63
    const int scol = (tid & 3) << 3;    // staging col (elements)

    u16* ldsA0 = As + wave * 512;
    u16* ldsA1 = As + 2048 + wave * 512;
    u16* ldsB0 = Bs + wave * 512;
    u16* ldsB1 = Bs + 2048 + wave * 512;

    const u16* bpt0 = Bw + (size_t)(colBase + srow) * K + scol;
    const u16* bpt1 = Bw + (size_t)(colBase + 64 + srow) * K + scol;
    const int arow0 = rowBase + srow;
    const int arow1 = arow0 + 64;
    const u16* ap0 = A + (size_t)arow0 * lda + scol;
    const u16* ap1 = A + (size_t)arow1 * lda + scol;

    const int wm = wave & 1, wn = wave >> 1;
    const int mB = wm * 64, nB = wn * 64;
    const int quad = lane >> 4, l16 = lane & 15;

    f32x4 acc[4][4];
#pragma unroll
    for (int a = 0; a < 4; a++)
#pragma unroll
        for (int b = 0; b < 4; b++)
#pragma unroll
            for (int r = 0; r < 4; r++) acc[a][b][r] = 0.f;

    for (int k0 = 0; k0 < K; k0 += 32) {
        if (CONV) {
            const int seg = k0 >> 11;                 // /H
            const int kk  = (k0 & (Hc - 1)) + scol;
            const int bbb = rowBase & ~(Sc - 1);      // batch start (flat row)
            const int r0  = arow0 + seg - 1;
            const int r1  = arow1 + seg - 1;
            const u16* g0 = ((unsigned)(r0 - bbb) < (unsigned)Sc) ? A + (size_t)r0 * lda + kk : zerobuf;
            const u16* g1 = ((unsigned)(r1 - bbb) < (unsigned)Sc) ? A + (size_t)r1 * lda + kk : zerobuf;
            gload16(g0, ldsA0);
            gload16(g1, ldsA1);
        } else {
            gload16(ap0 + k0, ldsA0);
            gload16(ap1 + k0, ldsA1);
        }
        gload16(bpt0 + k0, ldsB0);
        gload16(bpt1 + k0, ldsB1);
        __syncthreads();

        s16x8 af[4], bfr[4];
#pragma unroll
        for (int t = 0; t < 4; t++)
            af[t] = *(const s16x8*)(As + (mB + t * 16 + l16) * 32 + (quad << 3));
#pragma unroll
        for (int t = 0; t < 4; t++)
            bfr[t] = *(const s16x8*)(Bs + (nB + t * 16 + l16) * 32 + (quad << 3));
#pragma unroll
        for (int mt = 0; mt < 4; mt++)
#pragma unroll
            for (int nt = 0; nt < 4; nt++)
                acc[mt][nt] = __builtin_amdgcn_mfma_f32_16x16x32_bf16(af[mt], bfr[nt], acc[mt][nt], 0, 0, 0);
        __syncthreads();
    }

#pragma unroll
    for (int mt = 0; mt < 4; mt++) {
#pragma unroll
        for (int nt = 0; nt < 4; nt++) {
            const int col  = colBase + nB + nt * 16 + l16;
            const int row0 = rowBase + mB + mt * 16 + (quad << 2);
            const float bv = bias[col];
#pragma unroll
            for (int r = 0; r < 4; r++) {
                const size_t idx = (size_t)(row0 + r) * N + col;
                float v = acc[mt][nt][r] + bv;
                if (EPI == 0) {
                    Cb[idx] = f2bf(v);
                } else {
                    v += resid[idx];
                    Cf[idx]   = v;
                    xout[idx] = f2bf(v);
                }
            }
        }
    }
}

// ---------- LayerNorm over H=2048 (+ optional SiLU, + optional elementwise mul) ----------
__global__ __launch_bounds__(256)
void ln_fuse(const u16* __restrict__ in, u16* __restrict__ out,
             const float* __restrict__ g, const float* __restrict__ b,
             const u16* __restrict__ mul, int do_silu) {
    __shared__ float sred[4], qred[4];
    const int row = blockIdx.x, tid = threadIdx.x;
    const int lane = tid & 63, wave = tid >> 6;
    const size_t base = (size_t)row * Hc + tid * 8;

    s16x8 v8 = *(const s16x8*)(in + base);
    float x[8];
#pragma unroll
    for (int j = 0; j < 8; j++) x[j] = bf2f((u16)v8[j]);
    float s = 0.f, q = 0.f;
#pragma unroll
    for (int j = 0; j < 8; j++) { s += x[j]; q += x[j] * x[j]; }
#pragma unroll
    for (int off = 32; off > 0; off >>= 1) {
        s += __shfl_down(s, off);
        q += __shfl_down(q, off);
    }
    if (lane == 0) { sred[wave] = s; qred[wave] = q; }
    __syncthreads();
    const float St = sred[0] + sred[1] + sred[2] + sred[3];
    const float Qt = qred[0] + qred[1] + qred[2] + qred[3];
    const float mean = St * (1.0f / Hc);
    const float var  = Qt * (1.0f / Hc) - mean * mean;
    const float rs   = rsqrtf(var + 1e-5f);

    const int c = tid * 8;
    const float4 g0 = *(const float4*)(g + c), g1 = *(const float4*)(g + c + 4);
    const float4 b0 = *(const float4*)(b + c), b1 = *(const float4*)(b + c + 4);
    const float gg[8] = {g0.x, g0.y, g0.z, g0.w, g1.x, g1.y, g1.z, g1.w};
    const float bb[8] = {b0.x, b0.y, b0.z, b0.w, b1.x, b1.y, b1.z, b1.w};
    s16x8 m8;
    if (mul) m8 = *(const s16x8*)(mul + base);
    s16x8 o8;
#pragma unroll
    for (int j = 0; j < 8; j++) {
        float y = (x[j] - mean) * rs * gg[j] + bb[j];
        if (do_silu) y = y / (1.0f + __expf(-y));
        if (mul) y *= bf2f((u16)m8[j]);
        o8[j] = (short)f2bf(y);
    }
    *(s16x8*)(out + base) = o8;
}

// ---------- minGRU log-space CHUNKED parallel scan ----------
__device__ __forceinline__ void scan_step(float k, float p, float& ct, float& vt) {
    const float l1p = __logf(1.f + __expf(-fabsf(k)));
    ct = -(fmaxf(k, 0.f) + l1p);                      // -softplus(k)
    const float lg = (p >= 0.f) ? __logf(p + 0.5f)
                                : -(fmaxf(-p, 0.f) + __logf(1.f + __expf(-fabsf(p))));
    vt = -(fmaxf(-k, 0.f) + l1p) + lg;                // -softplus(-k) + log_g
}
__device__ __forceinline__ float laddexp(float a, float b) {
    const float m = fmaxf(a, b);
    return m + __logf(1.f + __expf(-fabsf(a - b)));
}

__global__ __launch_bounds__(256)
void scan_part1(const u16* __restrict__ kb, const u16* __restrict__ pb,
                float* __restrict__ Cc, float* __restrict__ Vv) {
    const int tid = threadIdx.x;
    const int hb = blockIdx.x & 7;          // H/256 = 8
    const int c  = (blockIdx.x >> 3) & 63;  // chunk
    const int b  = blockIdx.x >> 9;         // batch
    const int h  = hb * 256 + tid;
    size_t idx = (size_t)b * Sc * Hc + (size_t)(c * CL) * Hc + h;
    float C = 0.f, V = -1e30f;
#pragma unroll 4
    for (int t = 0; t < CL; t++) {
        float ct, vt;
        scan_step(bf2f(kb[idx]), bf2f(pb[idx]), ct, vt);
        V = laddexp(V + ct, vt);
        C += ct;
        idx += Hc;
    }
    const int chan = b * Hc + h;
    Cc[c * NCHAN + chan] = C;
    Vv[c * NCHAN + chan] = V;
}

__global__ __launch_bounds__(256)
void scan_mid(const float* __restrict__ Cc, const float* __restrict__ Vv,
              float* __restrict__ carry) {
    const int chan = blockIdx.x * 256 + threadIdx.x;  // 0..8191
    float lh = -0.69314718f;                          // log 0.5
    for (int c = 0; c < CH; c++) {
        carry[c * NCHAN + chan] = lh;
        lh = laddexp(lh + Cc[c * NCHAN + chan], Vv[c * NCHAN + chan]);
    }
}

__global__ __launch_bounds__(256)
void scan_part3(const u16* __restrict__ kb, const u16* __restrict__ pb,
                const float* __restrict__ carry, u16* __restrict__ out) {
    const int tid = threadIdx.x;
    const int hb = blockIdx.x & 7;
    const int c  = (blockIdx.x >> 3) & 63;
    const int b  = blockIdx.x >> 9;
    const int h  = hb * 256 + tid;
    size_t idx = (size_t)b * Sc * Hc + (size_t)(c * CL) * Hc + h;
    float lh = carry[c * NCHAN + (b * Hc + h)];
#pragma unroll 4
    for (int t = 0; t < CL; t++) {
        float ct, vt;
        scan_step(bf2f(kb[idx]), bf2f(pb[idx]), ct, vt);
        lh = laddexp(lh + ct, vt);
        out[idx] = f2bf(__expf(lh));
        idx += Hc;
    }
}

// ---------- casts ----------
__global__ __launch_bounds__(256)
void castf2b(const float* __restrict__ in, u16* __restrict__ out, int n) {
    const int i = (blockIdx.x * 256 + threadIdx.x) << 2;
    if (i >= n) return;
    const float4 v = *(const float4*)(in + i);
    u16x4 o;
    o.x = f2bf(v.x); o.y = f2bf(v.y); o.z = f2bf(v.z); o.w = f2bf(v.w);
    *(u16x4*)(out + i) = o;
}

// convW (H,H,3) -> wt (H, 3H): wt[o][k*H + i] = w[o][i][k]  (bf16)
__global__ __launch_bounds__(256)
void conv_tr(const float* __restrict__ w, u16* __restrict__ out) {
    const int idx = blockIdx.x * 256 + threadIdx.x;  // o*H + i
    const float* src = w + (size_t)idx * 3;
    const float a = src[0], b = src[1], c = src[2];
    const int o = idx >> 11, ii = idx & (Hc - 1);
    u16* dst = out + (size_t)o * (3 * Hc) + ii;
    dst[0]        = f2bf(a);
    dst[Hc]       = f2bf(b);
    dst[2 * Hc]   = f2bf(c);
}

// ---------- host ----------
static inline void launch_gemm8(int conv, const u16* A, const u16* Bw,
                                const float* bias, u16* C,
                                int M, int N, int K, int lda,
                                const u16* zero, hipStream_t s) {
    dim3 grid(N / 256, M / 256), blk(512);
    if (conv) gemm8<1><<<grid, blk, 0, s>>>(A, Bw, bias, C, M, N, K, lda, zero);
    else      gemm8<0><<<grid, blk, 0, s>>>(A, Bw, bias, C, M, N, K, lda, zero);
}

extern "C" void kernel_launch(void* const* d_in, const int* in_sizes, int n_in,
                              void* d_out, int out_size, void* d_ws, size_t ws_size,
                              hipStream_t stream) {
    (void)in_sizes; (void)n_in; (void)out_size; (void)ws_size;
    const float* x0    = (const float*)d_in[0];
    const float* Wp1   = (const float*)d_in[1];
    const float* bp1   = (const float*)d_in[2];
    const float* Wp2   = (const float*)d_in[3];
    const float* bp2   = (const float*)d_in[4];
    const float* convW = (const float*)d_in[5];
    const float* convb = (const float*)d_in[6];
    const float* Wz    = (const float*)d_in[7];
    const float* bz    = (const float*)d_in[8];
    const float* Wh    = (const float*)d_in[9];
    const float* bh    = (const float*)d_in[10];
    const float* Wd    = (const float*)d_in[11];
    const float* bd    = (const float*)d_in[12];
    const float* lng   = (const float*)d_in[13];
    const float* lnb   = (const float*)d_in[14];
    float* out = (float*)d_out;

    // ws layout (bytes)
    char* ws = (char*)d_ws;
    u16* wbuf = (u16*)(ws);                       // 12,582,912 elems (max weight: conv)
    u16* s1   = (u16*)(ws + 25165824);            // 16,777,216 elems each below
    u16* t1   = (u16*)(ws + 58720256);
    u16* s2   = (u16*)(ws + 92274688);            // doubles as kb
    u16* pbuf = (u16*)(ws + 125829120);
    u16* xb   = (u16*)(ws + 159383552);           // 8,388,608 elems
    u16* zero = (u16*)(ws + 176160768);           // 1 KiB zero page
    float* scanC = (float*)(ws + 176161792);      // 64*8192 f32
    float* scanV = (float*)(ws + 178258944);
    float* carry = (float*)(ws + 180356096);

    hipMemsetAsync(zero, 0, 1024, stream);
    castf2b<<<dim3((Mc * Dc / 4) / 256), dim3(256), 0, stream>>>(x0, xb, Mc * Dc);

    const size_t wpStride = (size_t)Hc * Dc;      // 2,097,152
    const size_t cvStride = (size_t)Hc * Hc * 3;  // 12,582,912
    const size_t wzStride = (size_t)Hc * Hc;      // 4,194,304
    const size_t wdStride = (size_t)Dc * Hc;      // 2,097,152

    for (int i = 0; i < Lc; ++i) {
        const float* g0 = lng + ((size_t)i * 4 + 0) * Hc; const float* be0 = lnb + ((size_t)i * 4 + 0) * Hc;
        const float* g1 = lng + ((size_t)i * 4 + 1) * Hc; const float* be1 = lnb + ((size_t)i * 4 + 1) * Hc;
        const float* g2 = lng + ((size_t)i * 4 + 2) * Hc; const float* be2 = lnb + ((size_t)i * 4 + 2) * Hc;
        const float* g3 = lng + ((size_t)i * 4 + 3) * Hc; const float* be3 = lnb + ((size_t)i * 4 + 3) * Hc;

        // strand 1: proj1 + LN0
        castf2b<<<dim3((int)(wpStride / 4 / 256)), dim3(256), 0, stream>>>(Wp1 + i * wpStride, wbuf, (int)wpStride);
        launch_gemm8(0, xb, wbuf, bp1 + (size_t)i * Hc, t1, Mc, Hc, Dc, Dc, zero, stream);
        ln_fuse<<<dim3(Mc), dim3(256), 0, stream>>>(t1, s1, g0, be0, nullptr, 0);

        // conv1d (as GEMM over K=3H) + LN1 + SiLU
        conv_tr<<<dim3((Hc * Hc) / 256), dim3(256), 0, stream>>>(convW + i * cvStride, wbuf);
        launch_gemm8(1, s1, wbuf, convb + (size_t)i * Hc, t1, Mc, Hc, 3 * Hc, Hc, zero, stream);
        ln_fuse<<<dim3(Mc), dim3(256), 0, stream>>>(t1, s1, g1, be1, nullptr, 1);

        // minGRU: k = s1@Wz^T+bz ; p = s1@Wh^T+bh ; chunked scan ; LN2
        castf2b<<<dim3((int)(wzStride / 4 / 256)), dim3(256), 0, stream>>>(Wz + i * wzStride, wbuf, (int)wzStride);
        launch_gemm8(0, s1, wbuf, bz + (size_t)i * Hc, s2, Mc, Hc, Hc, Hc, zero, stream);
        castf2b<<<dim3((int)(wzStride / 4 / 256)), dim3(256), 0, stream>>>(Wh + i * wzStride, wbuf, (int)wzStride);
        launch_gemm8(0, s1, wbuf, bh + (size_t)i * Hc, pbuf, Mc, Hc, Hc, Hc, zero, stream);
        scan_part1<<<dim3(2048), dim3(256), 0, stream>>>(s2, pbuf, scanC, scanV);
        scan_mid<<<dim3(32), dim3(256), 0, stream>>>(scanC, scanV, carry);
        scan_part3<<<dim3(2048), dim3(256), 0, stream>>>(s2, pbuf, carry, t1);
        ln_fuse<<<dim3(Mc), dim3(256), 0, stream>>>(t1, s1, g2, be2, nullptr, 0);

        // strand 2: proj2 + LN3 + SiLU, fused multiply by s1 -> s2
        castf2b<<<dim3((int)(wpStride / 4 / 256)), dim3(256), 0, stream>>>(Wp2 + i * wpStride, wbuf, (int)wpStride);
        launch_gemm8(0, xb, wbuf, bp2 + (size_t)i * Hc, t1, Mc, Hc, Dc, Dc, zero, stream);
        ln_fuse<<<dim3(Mc), dim3(256), 0, stream>>>(t1, s2, g3, be3, s1, 1);

        // down proj + bias + residual; write fp32 x to d_out and bf16 x to xb
        castf2b<<<dim3((int)(wdStride / 4 / 256)), dim3(256), 0, stream>>>(Wd + i * wdStride, wbuf, (int)wdStride);
        gemm_bt<0, 1><<<dim3(Dc / 128, Mc / 128), dim3(256), 0, stream>>>(
            s2, wbuf, bd + (size_t)i * Dc, nullptr, out,
            (i == 0) ? x0 : out, xb, Mc, Dc, Hc, Hc, zero);
    }
}

// Round 2
// 2941.706 us; speedup vs baseline: 1.0291x; 1.0291x over previous
//
#include <hip/hip_runtime.h>

// ---------- types / helpers ----------
typedef unsigned short u16;
typedef short  s16x8 __attribute__((ext_vector_type(8)));
typedef float  f32x4 __attribute__((ext_vector_type(4)));
typedef unsigned short u16x4 __attribute__((ext_vector_type(4)));

#define LDS_AS __attribute__((address_space(3)))
#define GLB_AS __attribute__((address_space(1)))

__device__ __forceinline__ float bf2f(u16 x) {
    unsigned u = ((unsigned)x) << 16;
    return __builtin_bit_cast(float, u);
}
__device__ __forceinline__ u16 f2bf(float f) {
    unsigned u = __builtin_bit_cast(unsigned, f);
    return (u16)((u + 0x7FFFu + ((u >> 16) & 1u)) >> 16);  // RNE
}
__device__ __forceinline__ void gload16(const u16* g, u16* l) {
    __builtin_amdgcn_global_load_lds((const GLB_AS unsigned int*)g,
                                     (LDS_AS unsigned int*)l, 16, 0, 0);
}

static constexpr int Lc = 4, Sc = 2048, Dc = 1024, Hc = 2048, Mc = 8192;
static constexpr int CH = 64, CL = 32;  // scan chunks / chunk length (CH*CL == Sc)
static constexpr int NCHAN = 4 * Hc;    // B*H = 8192 channels
static constexpr int KPW = 4096;        // fused k|p row width

// ============================================================================
// 256x256 8-phase GEMM (T1+T2+T3+T4+T5): C[M,N] = A[M,K] @ Bw[N,K]^T + bias
// BK=64, 512 threads (2Mx4N waves), 128KiB LDS double-buffer, XOR-swizzled
// LDS (pre-swizzled global source + swizzled ds_read), raw s_barrier +
// counted vmcnt(6), XCD-chunked blockIdx swizzle (contiguous ids per XCD
// -> A-panel L2 reuse across the 8 x-columns resident on one XCD).
// CONV=1: logical K=3*H over A[M,H] with row shift seg-1 and zero padding.
// EPI=1: v += resid(fp32); store fp32 to Cf and bf16 to xout.
// ============================================================================
#define BAR() __builtin_amdgcn_s_barrier()
#define VMCNT(n) asm volatile("s_waitcnt vmcnt(" #n ")" ::: "memory")

#define READ_A(d, BUF, MH)                                                     \
    _Pragma("unroll") for (int mf = 0; mf < 4; ++mf) {                         \
        d[mf][0] = *(const s16x8*)(aB0 + (BUF)*16384 + (MH)*4096 + mf*1024);   \
        d[mf][1] = *(const s16x8*)(aB1 + (BUF)*16384 + (MH)*4096 + mf*1024);   \
    }
#define READ_B(BUF, NH)                                                        \
    _Pragma("unroll") for (int jb = 0; jb < 2; ++jb) {                         \
        bq[jb][0] = *(const s16x8*)(bB0 + (BUF)*16384 + (NH)*2048 + jb*1024);  \
        bq[jb][1] = *(const s16x8*)(bB1 + (BUF)*16384 + (NH)*2048 + jb*1024);  \
    }
#define QUAD(a, MH, NH)                                                        \
    _Pragma("unroll") for (int mf = 0; mf < 4; ++mf)                           \
    _Pragma("unroll") for (int jb = 0; jb < 2; ++jb)                           \
    _Pragma("unroll") for (int kk = 0; kk < 2; ++kk)                           \
        acc[(MH)*4 + mf][(NH)*2 + jb] = __builtin_amdgcn_mfma_f32_16x16x32_bf16( \
            a[mf][kk], bq[jb][kk], acc[(MH)*4 + mf][(NH)*2 + jb], 0, 0, 0);

#define STAGE_A(BUF, H, KT) {                                                  \
    if (CONV) {                                                                \
        const int seg_ = ((KT)*64) >> 11;                                      \
        const int kb_  = ((KT)*64) & (Hc - 1);                                 \
        const int r0_  = convRow + (H)*128 + seg_;                             \
        const u16* s0_ = ((unsigned)(r0_ - bb) < (unsigned)Sc)                 \
                             ? A + (size_t)r0_ * lda + kb_ + scol : zerobuf;   \
        const u16* s1_ = ((unsigned)(r0_ + 8 - bb) < (unsigned)Sc)             \
                             ? A + (size_t)(r0_ + 8) * lda + kb_ + scol : zerobuf; \
        gload16(s0_, ldsA + (BUF)*16384 + (H)*8192);                           \
        gload16(s1_, ldsA + (BUF)*16384 + (H)*8192 + 512);                     \
    } else {                                                                   \
        const u16* s_ = srcA + (size_t)((H)*128) * lda + (KT)*64;              \
        gload16(s_,                   ldsA + (BUF)*16384 + (H)*8192);          \
        gload16(s_ + 8*(size_t)lda,   ldsA + (BUF)*16384 + (H)*8192 + 512);    \
    } }
#define STAGE_B(BUF, H, KT) {                                                  \
    const u16* s_ = srcB + (size_t)((H)*128) * K + (KT)*64;                    \
    gload16(s_,                 ldsB + (BUF)*16384 + (H)*8192);                \
    gload16(s_ + 8*(size_t)K,   ldsB + (BUF)*16384 + (H)*8192 + 512);          \
}

template <int CONV, int EPI>
__global__ __launch_bounds__(512, 2)
void gemm8(const u16* __restrict__ A, const u16* __restrict__ Bw,
           const float* __restrict__ bias, u16* __restrict__ Cb,
           float* __restrict__ Cf, const float* __restrict__ resid,
           u16* __restrict__ xout,
           int M, int N, int K, int lda, const u16* __restrict__ zerobuf) {
    (void)M;
    __shared__ __align__(16) u16 As[2][256][64];   // 64 KiB
    __shared__ __align__(16) u16 Bs[2][256][64];   // 64 KiB

    const int tid = threadIdx.x;
    const int w = tid >> 6, l = tid & 63;
    const int wm = w & 1, wn = w >> 1;           // 2 x 4 wave grid

    // ---- XCD-chunked bijective swizzle (nwg % 8 == 0 always here) ----
    const unsigned nwg = gridDim.x * gridDim.y;
    unsigned id = blockIdx.x + gridDim.x * blockIdx.y;
    id = (id & 7u) * (nwg >> 3) + (id >> 3);
    const int bx = (int)(id % gridDim.x);
    const int by = (int)(id / gridDim.x);
    const int rowBase = by * 256;
    const int colBase = bx * 256;

    // ---- staging (pre-swizzled source; LDS dest is linear) ----
    const int srow = w * 16 + (l >> 3);          // row within 128-row half
    const int scol = ((l & 7) ^ (l >> 3)) << 3;  // pre-swizzled element col
    const u16* srcB = Bw + (size_t)(colBase + srow) * K + scol;
    const u16* srcA = A + (size_t)(rowBase + srow) * lda + scol;   // non-conv
    u16* const ldsA = &As[0][0][0] + w * 1024;   // + BUF*16384 + H*8192 + j*512
    u16* const ldsB = &Bs[0][0][0] + w * 1024;
    const int bb = rowBase & ~(Sc - 1);          // batch start (conv)
    const int convRow = rowBase + srow - 1;      // + H*128 + seg

    // ---- fragment read bases (swizzled ds_read addresses) ----
    const int r16 = l & 15, slot = l >> 4;
    const int swz = (r16 & 7) << 4;                      // byte swizzle
    const int co0 = (((slot << 4)      ) ^ swz) >> 1;    // u16 units, kk=0
    const int co1 = (((slot << 4) | 64 ) ^ swz) >> 1;    // kk=1
    const u16* aB0 = &As[0][0][0] + (wm * 128 + r16) * 64 + co0;
    const u16* aB1 = &As[0][0][0] + (wm * 128 + r16) * 64 + co1;
    const u16* bB0 = &Bs[0][0][0] + (wn * 64  + r16) * 64 + co0;
    const u16* bB1 = &Bs[0][0][0] + (wn * 64  + r16) * 64 + co1;

    f32x4 acc[8][4];
#pragma unroll
    for (int m = 0; m < 8; ++m)
#pragma unroll
        for (int n = 0; n < 4; ++n)
#pragma unroll
            for (int r = 0; r < 4; ++r) acc[m][n][r] = 0.f;

    s16x8 a0[4][2], a1[4][2], bq[2][2];

    // ---- prologue: tile0 complete + tile1 {A0,A1,B0}; 3 half-tiles in flight
    STAGE_A(0, 0, 0); STAGE_A(0, 1, 0); STAGE_B(0, 0, 0); STAGE_B(0, 1, 0);
    VMCNT(4);
    STAGE_A(1, 0, 1); STAGE_A(1, 1, 1); STAGE_B(1, 0, 1);
    VMCNT(6);
    BAR();

    const int NI = K >> 7;                  // 2 K-tiles per iteration
    for (int i = 0; i < NI; ++i) {
        const int t1 = 2 * i + 1, t2 = 2 * i + 2, t3 = 2 * i + 3;
        const bool more = (i + 1 < NI);
        // -- phase 1: tile even (buf0), quad (0,0); stage t1.B1 -> buf1
        READ_A(a0, 0, 0); READ_B(0, 0);
        STAGE_B(1, 1, t1);
        BAR();
        __builtin_amdgcn_s_setprio(1); QUAD(a0, 0, 0); __builtin_amdgcn_s_setprio(0);
        BAR();
        // -- phase 2: quad (1,0)
        READ_A(a1, 0, 1);
        BAR();
        __builtin_amdgcn_s_setprio(1); QUAD(a1, 1, 0); __builtin_amdgcn_s_setprio(0);
        BAR();
        // -- phase 3: quad (0,1); stage t2.A0,t2.A1 -> buf0 (A fully read)
        READ_B(0, 1);
        if (more) { STAGE_A(0, 0, t2); STAGE_A(0, 1, t2); }
        BAR();
        __builtin_amdgcn_s_setprio(1); QUAD(a0, 0, 1); __builtin_amdgcn_s_setprio(0);
        BAR();
        // -- phase 4: quad (1,1); stage t2.B0; tile-boundary counted wait
        if (more) STAGE_B(0, 0, t2);
        BAR();
        __builtin_amdgcn_s_setprio(1); QUAD(a1, 1, 1); __builtin_amdgcn_s_setprio(0);
        if (more) { VMCNT(6); } else { VMCNT(0); }
        BAR();
        // -- phase 5: tile odd (buf1), quad (0,0); stage t2.B1
        READ_A(a0, 1, 0); READ_B(1, 0);
        if (more) STAGE_B(0, 1, t2);
        BAR();
        __builtin_amdgcn_s_setprio(1); QUAD(a0, 0, 0); __builtin_amdgcn_s_setprio(0);
        BAR();
        // -- phase 6: quad (1,0)
        READ_A(a1, 1, 1);
        BAR();
        __builtin_amdgcn_s_setprio(1); QUAD(a1, 1, 0); __builtin_amdgcn_s_setprio(0);
        BAR();
        // -- phase 7: quad (0,1); stage t3.A0,t3.A1 -> buf1
        READ_B(1, 1);
        if (more) { STAGE_A(1, 0, t3); STAGE_A(1, 1, t3); }
        BAR();
        __builtin_amdgcn_s_setprio(1); QUAD(a0, 0, 1); __builtin_amdgcn_s_setprio(0);
        BAR();
        // -- phase 8: quad (1,1); stage t3.B0; counted wait for next iter
        if (more) STAGE_B(1, 0, t3);
        BAR();
        __builtin_amdgcn_s_setprio(1); QUAD(a1, 1, 1); __builtin_amdgcn_s_setprio(0);
        if (more) VMCNT(6);
        BAR();
    }

    // ---- epilogue ----
    const int coll  = colBase + wn * 64 + r16;
    const int row00 = rowBase + wm * 128 + slot * 4;
#pragma unroll
    for (int m8 = 0; m8 < 8; ++m8) {
#pragma unroll
        for (int n4 = 0; n4 < 4; ++n4) {
            const int col = coll + n4 * 16;
            const float bv = bias[col];
            const int row0 = row00 + m8 * 16;
#pragma unroll
            for (int r = 0; r < 4; ++r) {
                const size_t idx = (size_t)(row0 + r) * N + col;
                float v = acc[m8][n4][r] + bv;
                if (EPI == 0) {
                    Cb[idx] = f2bf(v);
                } else {
                    v += resid[idx];
                    Cf[idx]   = v;
                    xout[idx] = f2bf(v);
                }
            }
        }
    }
}

// ---------- LayerNorm over H=2048 (+ optional SiLU, + optional elementwise mul) ----------
__global__ __launch_bounds__(256)
void ln_fuse(const u16* __restrict__ in, u16* __restrict__ out,
             const float* __restrict__ g, const float* __restrict__ b,
             const u16* __restrict__ mul, int do_silu) {
    __shared__ float sred[4], qred[4];
    const int row = blockIdx.x, tid = threadIdx.x;
    const int lane = tid & 63, wave = tid >> 6;
    const size_t base = (size_t)row * Hc + tid * 8;

    s16x8 v8 = *(const s16x8*)(in + base);
    float x[8];
#pragma unroll
    for (int j = 0; j < 8; j++) x[j] = bf2f((u16)v8[j]);
    float s = 0.f, q = 0.f;
#pragma unroll
    for (int j = 0; j < 8; j++) { s += x[j]; q += x[j] * x[j]; }
#pragma unroll
    for (int off = 32; off > 0; off >>= 1) {
        s += __shfl_down(s, off);
        q += __shfl_down(q, off);
    }
    if (lane == 0) { sred[wave] = s; qred[wave] = q; }
    __syncthreads();
    const float St = sred[0] + sred[1] + sred[2] + sred[3];
    const float Qt = qred[0] + qred[1] + qred[2] + qred[3];
    const float mean = St * (1.0f / Hc);
    const float var  = Qt * (1.0f / Hc) - mean * mean;
    const float rs   = rsqrtf(var + 1e-5f);

    const int c = tid * 8;
    const float4 g0 = *(const float4*)(g + c), g1 = *(const float4*)(g + c + 4);
    const float4 b0 = *(const float4*)(b + c), b1 = *(const float4*)(b + c + 4);
    const float gg[8] = {g0.x, g0.y, g0.z, g0.w, g1.x, g1.y, g1.z, g1.w};
    const float bb[8] = {b0.x, b0.y, b0.z, b0.w, b1.x, b1.y, b1.z, b1.w};
    s16x8 m8;
    if (mul) m8 = *(const s16x8*)(mul + base);
    s16x8 o8;
#pragma unroll
    for (int j = 0; j < 8; j++) {
        float y = (x[j] - mean) * rs * gg[j] + bb[j];
        if (do_silu) y = y / (1.0f + __expf(-y));
        if (mul) y *= bf2f((u16)m8[j]);
        o8[j] = (short)f2bf(y);
    }
    *(s16x8*)(out + base) = o8;
}

// ---------- minGRU log-space CHUNKED parallel scan (fused k|p input, width 4096) ----------
__device__ __forceinline__ void scan_step(float k, float p, float& ct, float& vt) {
    const float l1p = __logf(1.f + __expf(-fabsf(k)));
    ct = -(fmaxf(k, 0.f) + l1p);                      // -softplus(k)
    const float lg = (p >= 0.f) ? __logf(p + 0.5f)
                                : -(fmaxf(-p, 0.f) + __logf(1.f + __expf(-fabsf(p))));
    vt = -(fmaxf(-k, 0.f) + l1p) + lg;                // -softplus(-k) + log_g
}
__device__ __forceinline__ float laddexp(float a, float b) {
    const float m = fmaxf(a, b);
    return m + __logf(1.f + __expf(-fabsf(a - b)));
}

__global__ __launch_bounds__(256)
void scan_part1(const u16* __restrict__ kp,
                float* __restrict__ Cc, float* __restrict__ Vv) {
    const int tid = threadIdx.x;
    const int hb = blockIdx.x & 7;          // H/256 = 8
    const int c  = (blockIdx.x >> 3) & 63;  // chunk
    const int b  = blockIdx.x >> 9;         // batch
    const int h  = hb * 256 + tid;
    size_t idx = (size_t)(b * Sc + c * CL) * KPW + h;
    float C = 0.f, V = -1e30f;
#pragma unroll 4
    for (int t = 0; t < CL; t++) {
        float ct, vt;
        scan_step(bf2f(kp[idx]), bf2f(kp[idx + Hc]), ct, vt);
        V = laddexp(V + ct, vt);
        C += ct;
        idx += KPW;
    }
    const int chan = b * Hc + h;
    Cc[c * NCHAN + chan] = C;
    Vv[c * NCHAN + chan] = V;
}

__global__ __launch_bounds__(256)
void scan_mid(const float* __restrict__ Cc, const float* __restrict__ Vv,
              float* __restrict__ carry) {
    const int chan = blockIdx.x * 256 + threadIdx.x;  // 0..8191
    float lh = -0.69314718f;                          // log 0.5
    for (int c = 0; c < CH; c++) {
        carry[c * NCHAN + chan] = lh;
        lh = laddexp(lh + Cc[c * NCHAN + chan], Vv[c * NCHAN + chan]);
    }
}

__global__ __launch_bounds__(256)
void scan_part3(const u16* __restrict__ kp,
                const float* __restrict__ carry, u16* __restrict__ out) {
    const int tid = threadIdx.x;
    const int hb = blockIdx.x & 7;
    const int c  = (blockIdx.x >> 3) & 63;
    const int b  = blockIdx.x >> 9;
    const int h  = hb * 256 + tid;
    size_t idx = (size_t)(b * Sc + c * CL) * KPW + h;
    size_t odx = (size_t)(b * Sc + c * CL) * Hc + h;
    float lh = carry[c * NCHAN + (b * Hc + h)];
#pragma unroll 4
    for (int t = 0; t < CL; t++) {
        float ct, vt;
        scan_step(bf2f(kp[idx]), bf2f(kp[idx + Hc]), ct, vt);
        lh = laddexp(lh + ct, vt);
        out[odx] = f2bf(__expf(lh));
        idx += KPW;
        odx += Hc;
    }
}

// ---------- casts ----------
__global__ __launch_bounds__(256)
void castf2b(const float* __restrict__ in, u16* __restrict__ out, int n) {
    const int i = (blockIdx.x * 256 + threadIdx.x) << 2;
    if (i >= n) return;
    const float4 v = *(const float4*)(in + i);
    u16x4 o;
    o.x = f2bf(v.x); o.y = f2bf(v.y); o.z = f2bf(v.z); o.w = f2bf(v.w);
    *(u16x4*)(out + i) = o;
}

// convW (H,H,3) -> wt (H, 3H): wt[o][k*H + i] = w[o][i][k]  (bf16)
__global__ __launch_bounds__(256)
void conv_tr(const float* __restrict__ w, u16* __restrict__ out) {
    const int idx = blockIdx.x * 256 + threadIdx.x;  // o*H + i
    const float* src = w + (size_t)idx * 3;
    const float a = src[0], b = src[1], c = src[2];
    const int o = idx >> 11, ii = idx & (Hc - 1);
    u16* dst = out + (size_t)o * (3 * Hc) + ii;
    dst[0]        = f2bf(a);
    dst[Hc]       = f2bf(b);
    dst[2 * Hc]   = f2bf(c);
}

// ---------- host ----------
static inline void launch_gemm8(int conv, int epi,
                                const u16* A, const u16* Bw, const float* bias,
                                u16* Cb, float* Cf, const float* resid, u16* xout,
                                int M, int N, int K, int lda,
                                const u16* zero, hipStream_t s) {
    dim3 grid(N / 256, M / 256), blk(512);
    if (conv)
        gemm8<1, 0><<<grid, blk, 0, s>>>(A, Bw, bias, Cb, Cf, resid, xout, M, N, K, lda, zero);
    else if (epi)
        gemm8<0, 1><<<grid, blk, 0, s>>>(A, Bw, bias, Cb, Cf, resid, xout, M, N, K, lda, zero);
    else
        gemm8<0, 0><<<grid, blk, 0, s>>>(A, Bw, bias, Cb, Cf, resid, xout, M, N, K, lda, zero);
}

extern "C" void kernel_launch(void* const* d_in, const int* in_sizes, int n_in,
                              void* d_out, int out_size, void* d_ws, size_t ws_size,
                              hipStream_t stream) {
    (void)in_sizes; (void)n_in; (void)out_size; (void)ws_size;
    const float* x0    = (const float*)d_in[0];
    const float* Wp1   = (const float*)d_in[1];
    const float* bp1   = (const float*)d_in[2];
    const float* Wp2   = (const float*)d_in[3];
    const float* bp2   = (const float*)d_in[4];
    const float* convW = (const float*)d_in[5];
    const float* convb = (const float*)d_in[6];
    const float* Wz    = (const float*)d_in[7];
    const float* bz    = (const float*)d_in[8];
    const float* Wh    = (const float*)d_in[9];
    const float* bh    = (const float*)d_in[10];
    const float* Wd    = (const float*)d_in[11];
    const float* bd    = (const float*)d_in[12];
    const float* lng   = (const float*)d_in[13];
    const float* lnb   = (const float*)d_in[14];
    float* out = (float*)d_out;

    // ws layout (bytes)
    char* ws = (char*)d_ws;
    u16* wbuf = (u16*)(ws);                       // 12,582,912 elems (max weight: conv)
    u16* s1   = (u16*)(ws + 25165824);            // [M][H] bf16
    u16* t1   = (u16*)(ws + 58720256);            // [M][H] bf16
    u16* kp   = (u16*)(ws + 92274688);            // [M][4096] bf16 (k | p fused, 64 MB)
    u16* s2   = kp;                               // reused as [M][H] after scan
    u16* xb   = (u16*)(ws + 159383552);           // [M][D] bf16
    u16* zero = (u16*)(ws + 176160768);           // 1 KiB zero page
    float* scanC = (float*)(ws + 176161792);      // 64*8192 f32
    float* scanV = (float*)(ws + 178258944);
    float* carry = (float*)(ws + 180356096);
    float* bias2 = (float*)(ws + 182453248);      // 4096 f32 ([bz | bh])

    hipMemsetAsync(zero, 0, 1024, stream);
    castf2b<<<dim3((Mc * Dc / 4) / 256), dim3(256), 0, stream>>>(x0, xb, Mc * Dc);

    const size_t wpStride = (size_t)Hc * Dc;      // 2,097,152
    const size_t cvStride = (size_t)Hc * Hc * 3;  // 12,582,912
    const size_t wzStride = (size_t)Hc * Hc;      // 4,194,304
    const size_t wdStride = (size_t)Dc * Hc;      // 2,097,152

    for (int i = 0; i < Lc; ++i) {
        const float* g0 = lng + ((size_t)i * 4 + 0) * Hc; const float* be0 = lnb + ((size_t)i * 4 + 0) * Hc;
        const float* g1 = lng + ((size_t)i * 4 + 1) * Hc; const float* be1 = lnb + ((size_t)i * 4 + 1) * Hc;
        const float* g2 = lng + ((size_t)i * 4 + 2) * Hc; const float* be2 = lnb + ((size_t)i * 4 + 2) * Hc;
        const float* g3 = lng + ((size_t)i * 4 + 3) * Hc; const float* be3 = lnb + ((size_t)i * 4 + 3) * Hc;

        // strand 1: proj1 + LN0
        castf2b<<<dim3((int)(wpStride / 4 / 256)), dim3(256), 0, stream>>>(Wp1 + i * wpStride, wbuf, (int)wpStride);
        launch_gemm8(0, 0, xb, wbuf, bp1 + (size_t)i * Hc, t1, nullptr, nullptr, nullptr,
                     Mc, Hc, Dc, Dc, zero, stream);
        ln_fuse<<<dim3(Mc), dim3(256), 0, stream>>>(t1, s1, g0, be0, nullptr, 0);

        // conv1d (as GEMM over K=3H) + LN1 + SiLU
        conv_tr<<<dim3((Hc * Hc) / 256), dim3(256), 0, stream>>>(convW + i * cvStride, wbuf);
        launch_gemm8(1, 0, s1, wbuf, convb + (size_t)i * Hc, t1, nullptr, nullptr, nullptr,
                     Mc, Hc, 3 * Hc, Hc, zero, stream);
        ln_fuse<<<dim3(Mc), dim3(256), 0, stream>>>(t1, s1, g1, be1, nullptr, 1);

        // minGRU: fused [k|p] = s1 @ [Wz|Wh]^T + [bz|bh]  (one N=4096 GEMM)
        castf2b<<<dim3((int)(wzStride / 4 / 256)), dim3(256), 0, stream>>>(Wz + i * wzStride, wbuf, (int)wzStride);
        castf2b<<<dim3((int)(wzStride / 4 / 256)), dim3(256), 0, stream>>>(Wh + i * wzStride, wbuf + wzStride, (int)wzStride);
        hipMemcpyAsync(bias2,        bz + (size_t)i * Hc, Hc * sizeof(float), hipMemcpyDeviceToDevice, stream);
        hipMemcpyAsync(bias2 + Hc,   bh + (size_t)i * Hc, Hc * sizeof(float), hipMemcpyDeviceToDevice, stream);
        launch_gemm8(0, 0, s1, wbuf, bias2, kp, nullptr, nullptr, nullptr,
                     Mc, KPW, Hc, Hc, zero, stream);
        scan_part1<<<dim3(2048), dim3(256), 0, stream>>>(kp, scanC, scanV);
        scan_mid<<<dim3(32), dim3(256), 0, stream>>>(scanC, scanV, carry);
        scan_part3<<<dim3(2048), dim3(256), 0, stream>>>(kp, carry, t1);
        ln_fuse<<<dim3(Mc), dim3(256), 0, stream>>>(t1, s1, g2, be2, nullptr, 0);

        // strand 2: proj2 + LN3 + SiLU, fused multiply by s1 -> s2 (kp region, free now)
        castf2b<<<dim3((int)(wpStride / 4 / 256)), dim3(256), 0, stream>>>(Wp2 + i * wpStride, wbuf, (int)wpStride);
        launch_gemm8(0, 0, xb, wbuf, bp2 + (size_t)i * Hc, t1, nullptr, nullptr, nullptr,
                     Mc, Hc, Dc, Dc, zero, stream);
        ln_fuse<<<dim3(Mc), dim3(256), 0, stream>>>(t1, s2, g3, be3, s1, 1);

        // down proj + bias + residual; write fp32 x to d_out and bf16 x to xb
        castf2b<<<dim3((int)(wdStride / 4 / 256)), dim3(256), 0, stream>>>(Wd + i * wdStride, wbuf, (int)wdStride);
        launch_gemm8(0, 1, s2, wbuf, bd + (size_t)i * Dc, nullptr, out,
                     (i == 0) ? x0 : out, xb, Mc, Dc, Hc, Hc, zero, stream);
    }
}

// Round 3
// 2923.182 us; speedup vs baseline: 1.0356x; 1.0063x over previous
//
#include <hip/hip_runtime.h>

// ---------- types / helpers ----------
typedef unsigned short u16;
typedef short  s16x8 __attribute__((ext_vector_type(8)));
typedef float  f32x4 __attribute__((ext_vector_type(4)));
typedef unsigned short u16x4 __attribute__((ext_vector_type(4)));

#define LDS_AS __attribute__((address_space(3)))
#define GLB_AS __attribute__((address_space(1)))

__device__ __forceinline__ float bf2f(u16 x) {
    unsigned u = ((unsigned)x) << 16;
    return __builtin_bit_cast(float, u);
}
__device__ __forceinline__ u16 f2bf(float f) {
    unsigned u = __builtin_bit_cast(unsigned, f);
    return (u16)((u + 0x7FFFu + ((u >> 16) & 1u)) >> 16);  // RNE
}
__device__ __forceinline__ void gload16(const u16* g, u16* l) {
    __builtin_amdgcn_global_load_lds((const GLB_AS unsigned int*)g,
                                     (LDS_AS unsigned int*)l, 16, 0, 0);
}

static constexpr int Lc = 4, Sc = 2048, Dc = 1024, Hc = 2048, Mc = 8192;
static constexpr int CH = 64, CL = 32;  // scan chunks / chunk length (CH*CL == Sc)
static constexpr int NCHAN = 4 * Hc;    // B*H = 8192 channels
static constexpr int KPW = 4096;        // fused dual-output row width

// ============================================================================
// 256x256 8-phase GEMM (T1+T2+T3+T4+T5): C[M,N] = A[M,K] @ Bw[N,K]^T + bias
// This round: template-parity sync — explicit s_waitcnt lgkmcnt(0) +
// sched_barrier(0) after the pre-MFMA barrier (and lgkmcnt(8) before the
// barrier on the 12-ds_read phases), exactly as the verified 62%-MfmaUtil
// reference schedule prescribes.
// ============================================================================
#define BAR() __builtin_amdgcn_s_barrier()
#define VMCNT(n) asm volatile("s_waitcnt vmcnt(" #n ")" ::: "memory")
#define LGK8() asm volatile("s_waitcnt lgkmcnt(8)" ::: "memory")
#define WAIT0()                                                                \
    do {                                                                       \
        asm volatile("s_waitcnt lgkmcnt(0)" ::: "memory");                     \
        __builtin_amdgcn_sched_barrier(0);                                     \
    } while (0)

#define READ_A(d, BUF, MH)                                                     \
    _Pragma("unroll") for (int mf = 0; mf < 4; ++mf) {                         \
        d[mf][0] = *(const s16x8*)(aB0 + (BUF)*16384 + (MH)*4096 + mf*1024);   \
        d[mf][1] = *(const s16x8*)(aB1 + (BUF)*16384 + (MH)*4096 + mf*1024);   \
    }
#define READ_B(BUF, NH)                                                        \
    _Pragma("unroll") for (int jb = 0; jb < 2; ++jb) {                         \
        bq[jb][0] = *(const s16x8*)(bB0 + (BUF)*16384 + (NH)*2048 + jb*1024);  \
        bq[jb][1] = *(const s16x8*)(bB1 + (BUF)*16384 + (NH)*2048 + jb*1024);  \
    }
#define QUAD(a, MH, NH)                                                        \
    _Pragma("unroll") for (int mf = 0; mf < 4; ++mf)                           \
    _Pragma("unroll") for (int jb = 0; jb < 2; ++jb)                           \
    _Pragma("unroll") for (int kk = 0; kk < 2; ++kk)                           \
        acc[(MH)*4 + mf][(NH)*2 + jb] = __builtin_amdgcn_mfma_f32_16x16x32_bf16( \
            a[mf][kk], bq[jb][kk], acc[(MH)*4 + mf][(NH)*2 + jb], 0, 0, 0);

#define STAGE_A(BUF, H, KT) {                                                  \
    if (CONV) {                                                                \
        const int seg_ = ((KT)*64) >> 11;                                      \
        const int kb_  = ((KT)*64) & (Hc - 1);                                 \
        const int r0_  = convRow + (H)*128 + seg_;                             \
        const u16* s0_ = ((unsigned)(r0_ - bb) < (unsigned)Sc)                 \
                             ? A + (size_t)r0_ * lda + kb_ + scol : zerobuf;   \
        const u16* s1_ = ((unsigned)(r0_ + 8 - bb) < (unsigned)Sc)             \
                             ? A + (size_t)(r0_ + 8) * lda + kb_ + scol : zerobuf; \
        gload16(s0_, ldsA + (BUF)*16384 + (H)*8192);                           \
        gload16(s1_, ldsA + (BUF)*16384 + (H)*8192 + 512);                     \
    } else {                                                                   \
        const u16* s_ = srcA + (size_t)((H)*128) * lda + (KT)*64;              \
        gload16(s_,                   ldsA + (BUF)*16384 + (H)*8192);          \
        gload16(s_ + 8*(size_t)lda,   ldsA + (BUF)*16384 + (H)*8192 + 512);    \
    } }
#define STAGE_B(BUF, H, KT) {                                                  \
    const u16* s_ = srcB + (size_t)((H)*128) * K + (KT)*64;                    \
    gload16(s_,                 ldsB + (BUF)*16384 + (H)*8192);                \
    gload16(s_ + 8*(size_t)K,   ldsB + (BUF)*16384 + (H)*8192 + 512);          \
}

template <int CONV, int EPI>
__global__ __launch_bounds__(512, 2)
void gemm8(const u16* __restrict__ A, const u16* __restrict__ Bw,
           const float* __restrict__ bias, u16* __restrict__ Cb,
           float* __restrict__ Cf, const float* __restrict__ resid,
           u16* __restrict__ xout,
           int M, int N, int K, int lda, const u16* __restrict__ zerobuf) {
    (void)M;
    __shared__ __align__(16) u16 As[2][256][64];   // 64 KiB
    __shared__ __align__(16) u16 Bs[2][256][64];   // 64 KiB

    const int tid = threadIdx.x;
    const int w = tid >> 6, l = tid & 63;
    const int wm = w & 1, wn = w >> 1;           // 2 x 4 wave grid

    // ---- XCD-chunked bijective swizzle (nwg % 8 == 0 always here) ----
    const unsigned nwg = gridDim.x * gridDim.y;
    unsigned id = blockIdx.x + gridDim.x * blockIdx.y;
    id = (id & 7u) * (nwg >> 3) + (id >> 3);
    const int bx = (int)(id % gridDim.x);
    const int by = (int)(id / gridDim.x);
    const int rowBase = by * 256;
    const int colBase = bx * 256;

    // ---- staging (pre-swizzled source; LDS dest is linear) ----
    const int srow = w * 16 + (l >> 3);          // row within 128-row half
    const int scol = ((l & 7) ^ (l >> 3)) << 3;  // pre-swizzled element col
    const u16* srcB = Bw + (size_t)(colBase + srow) * K + scol;
    const u16* srcA = A + (size_t)(rowBase + srow) * lda + scol;   // non-conv
    u16* const ldsA = &As[0][0][0] + w * 1024;   // + BUF*16384 + H*8192 + j*512
    u16* const ldsB = &Bs[0][0][0] + w * 1024;
    const int bb = rowBase & ~(Sc - 1);          // batch start (conv)
    const int convRow = rowBase + srow - 1;      // + H*128 + seg

    // ---- fragment read bases (swizzled ds_read addresses) ----
    const int r16 = l & 15, slot = l >> 4;
    const int swz = (r16 & 7) << 4;                      // byte swizzle
    const int co0 = (((slot << 4)      ) ^ swz) >> 1;    // u16 units, kk=0
    const int co1 = (((slot << 4) | 64 ) ^ swz) >> 1;    // kk=1
    const u16* aB0 = &As[0][0][0] + (wm * 128 + r16) * 64 + co0;
    const u16* aB1 = &As[0][0][0] + (wm * 128 + r16) * 64 + co1;
    const u16* bB0 = &Bs[0][0][0] + (wn * 64  + r16) * 64 + co0;
    const u16* bB1 = &Bs[0][0][0] + (wn * 64  + r16) * 64 + co1;

    f32x4 acc[8][4];
#pragma unroll
    for (int m = 0; m < 8; ++m)
#pragma unroll
        for (int n = 0; n < 4; ++n)
#pragma unroll
            for (int r = 0; r < 4; ++r) acc[m][n][r] = 0.f;

    s16x8 a0[4][2], a1[4][2], bq[2][2];

    // ---- prologue: tile0 complete + tile1 {A0,A1,B0}; 3 half-tiles in flight
    STAGE_A(0, 0, 0); STAGE_A(0, 1, 0); STAGE_B(0, 0, 0); STAGE_B(0, 1, 0);
    VMCNT(4);
    STAGE_A(1, 0, 1); STAGE_A(1, 1, 1); STAGE_B(1, 0, 1);
    VMCNT(6);
    BAR();

    const int NI = K >> 7;                  // 2 K-tiles per iteration
    for (int i = 0; i < NI; ++i) {
        const int t1 = 2 * i + 1, t2 = 2 * i + 2, t3 = 2 * i + 3;
        const bool more = (i + 1 < NI);
        // -- phase 1: tile even (buf0), quad (0,0); stage t1.B1 -> buf1
        READ_A(a0, 0, 0); READ_B(0, 0);
        STAGE_B(1, 1, t1);
        LGK8();
        BAR(); WAIT0();
        __builtin_amdgcn_s_setprio(1); QUAD(a0, 0, 0); __builtin_amdgcn_s_setprio(0);
        BAR();
        // -- phase 2: quad (1,0)
        READ_A(a1, 0, 1);
        BAR(); WAIT0();
        __builtin_amdgcn_s_setprio(1); QUAD(a1, 1, 0); __builtin_amdgcn_s_setprio(0);
        BAR();
        // -- phase 3: quad (0,1); stage t2.A0,t2.A1 -> buf0 (A fully read)
        READ_B(0, 1);
        if (more) { STAGE_A(0, 0, t2); STAGE_A(0, 1, t2); }
        BAR(); WAIT0();
        __builtin_amdgcn_s_setprio(1); QUAD(a0, 0, 1); __builtin_amdgcn_s_setprio(0);
        BAR();
        // -- phase 4: quad (1,1); stage t2.B0; tile-boundary counted wait
        if (more) STAGE_B(0, 0, t2);
        BAR();
        __builtin_amdgcn_s_setprio(1); QUAD(a1, 1, 1); __builtin_amdgcn_s_setprio(0);
        if (more) { VMCNT(6); } else { VMCNT(0); }
        BAR();
        // -- phase 5: tile odd (buf1), quad (0,0); stage t2.B1
        READ_A(a0, 1, 0); READ_B(1, 0);
        if (more) STAGE_B(0, 1, t2);
        LGK8();
        BAR(); WAIT0();
        __builtin_amdgcn_s_setprio(1); QUAD(a0, 0, 0); __builtin_amdgcn_s_setprio(0);
        BAR();
        // -- phase 6: quad (1,0)
        READ_A(a1, 1, 1);
        BAR(); WAIT0();
        __builtin_amdgcn_s_setprio(1); QUAD(a1, 1, 0); __builtin_amdgcn_s_setprio(0);
        BAR();
        // -- phase 7: quad (0,1); stage t3.A0,t3.A1 -> buf1
        READ_B(1, 1);
        if (more) { STAGE_A(1, 0, t3); STAGE_A(1, 1, t3); }
        BAR(); WAIT0();
        __builtin_amdgcn_s_setprio(1); QUAD(a0, 0, 1); __builtin_amdgcn_s_setprio(0);
        BAR();
        // -- phase 8: quad (1,1); stage t3.B0; counted wait for next iter
        if (more) STAGE_B(1, 0, t3);
        BAR();
        __builtin_amdgcn_s_setprio(1); QUAD(a1, 1, 1); __builtin_amdgcn_s_setprio(0);
        if (more) VMCNT(6);
        BAR();
    }

    // ---- epilogue ----
    const int coll  = colBase + wn * 64 + r16;
    const int row00 = rowBase + wm * 128 + slot * 4;
#pragma unroll
    for (int m8 = 0; m8 < 8; ++m8) {
#pragma unroll
        for (int n4 = 0; n4 < 4; ++n4) {
            const int col = coll + n4 * 16;
            const float bv = bias[col];
            const int row0 = row00 + m8 * 16;
#pragma unroll
            for (int r = 0; r < 4; ++r) {
                const size_t idx = (size_t)(row0 + r) * N + col;
                float v = acc[m8][n4][r] + bv;
                if (EPI == 0) {
                    Cb[idx] = f2bf(v);
                } else {
                    v += resid[idx];
                    Cf[idx]   = v;
                    xout[idx] = f2bf(v);
                }
            }
        }
    }
}

// ---------- LayerNorm over H=2048 (+ optional SiLU, + optional elementwise mul) ----------
// instride: row stride of `in` (Hc normally; KPW for fused dual-output buffers)
__global__ __launch_bounds__(256)
void ln_fuse(const u16* __restrict__ in, int instride, u16* __restrict__ out,
             const float* __restrict__ g, const float* __restrict__ b,
             const u16* __restrict__ mul, int do_silu) {
    __shared__ float sred[4], qred[4];
    const int row = blockIdx.x, tid = threadIdx.x;
    const int lane = tid & 63, wave = tid >> 6;
    const size_t ibase = (size_t)row * instride + tid * 8;
    const size_t obase = (size_t)row * Hc + tid * 8;

    s16x8 v8 = *(const s16x8*)(in + ibase);
    float x[8];
#pragma unroll
    for (int j = 0; j < 8; j++) x[j] = bf2f((u16)v8[j]);
    float s = 0.f, q = 0.f;
#pragma unroll
    for (int j = 0; j < 8; j++) { s += x[j]; q += x[j] * x[j]; }
#pragma unroll
    for (int off = 32; off > 0; off >>= 1) {
        s += __shfl_down(s, off);
        q += __shfl_down(q, off);
    }
    if (lane == 0) { sred[wave] = s; qred[wave] = q; }
    __syncthreads();
    const float St = sred[0] + sred[1] + sred[2] + sred[3];
    const float Qt = qred[0] + qred[1] + qred[2] + qred[3];
    const float mean = St * (1.0f / Hc);
    const float var  = Qt * (1.0f / Hc) - mean * mean;
    const float rs   = rsqrtf(var + 1e-5f);

    const int c = tid * 8;
    const float4 g0 = *(const float4*)(g + c), g1 = *(const float4*)(g + c + 4);
    const float4 b0 = *(const float4*)(b + c), b1 = *(const float4*)(b + c + 4);
    const float gg[8] = {g0.x, g0.y, g0.z, g0.w, g1.x, g1.y, g1.z, g1.w};
    const float bb[8] = {b0.x, b0.y, b0.z, b0.w, b1.x, b1.y, b1.z, b1.w};
    s16x8 m8;
    if (mul) m8 = *(const s16x8*)(mul + obase);
    s16x8 o8;
#pragma unroll
    for (int j = 0; j < 8; j++) {
        float y = (x[j] - mean) * rs * gg[j] + bb[j];
        if (do_silu) y = y / (1.0f + __expf(-y));
        if (mul) y *= bf2f((u16)m8[j]);
        o8[j] = (short)f2bf(y);
    }
    *(s16x8*)(out + obase) = o8;
}

// ---------- minGRU log-space CHUNKED parallel scan (fused k|p input, width 4096) ----------
__device__ __forceinline__ void scan_step(float k, float p, float& ct, float& vt) {
    const float l1p = __logf(1.f + __expf(-fabsf(k)));
    ct = -(fmaxf(k, 0.f) + l1p);                      // -softplus(k)
    const float lg = (p >= 0.f) ? __logf(p + 0.5f)
                                : -(fmaxf(-p, 0.f) + __logf(1.f + __expf(-fabsf(p))));
    vt = -(fmaxf(-k, 0.f) + l1p) + lg;                // -softplus(-k) + log_g
}
__device__ __forceinline__ float laddexp(float a, float b) {
    const float m = fmaxf(a, b);
    return m + __logf(1.f + __expf(-fabsf(a - b)));
}

__global__ __launch_bounds__(256)
void scan_part1(const u16* __restrict__ kp,
                float* __restrict__ Cc, float* __restrict__ Vv) {
    const int tid = threadIdx.x;
    const int hb = blockIdx.x & 7;          // H/256 = 8
    const int c  = (blockIdx.x >> 3) & 63;  // chunk
    const int b  = blockIdx.x >> 9;         // batch
    const int h  = hb * 256 + tid;
    size_t idx = (size_t)(b * Sc + c * CL) * KPW + h;
    float C = 0.f, V = -1e30f;
#pragma unroll 4
    for (int t = 0; t < CL; t++) {
        float ct, vt;
        scan_step(bf2f(kp[idx]), bf2f(kp[idx + Hc]), ct, vt);
        V = laddexp(V + ct, vt);
        C += ct;
        idx += KPW;
    }
    const int chan = b * Hc + h;
    Cc[c * NCHAN + chan] = C;
    Vv[c * NCHAN + chan] = V;
}

// batched-prefetch serial chunk-scan: 8 (C,V) pairs in flight per thread
__global__ __launch_bounds__(256)
void scan_mid(const float* __restrict__ Cc, const float* __restrict__ Vv,
              float* __restrict__ carry) {
    const int chan = blockIdx.x * 256 + threadIdx.x;  // 0..8191
    float lh = -0.69314718f;                          // log 0.5
    for (int cb = 0; cb < CH; cb += 8) {
        float Cr[8], Vr[8];
#pragma unroll
        for (int j = 0; j < 8; j++) {
            Cr[j] = Cc[(cb + j) * NCHAN + chan];
            Vr[j] = Vv[(cb + j) * NCHAN + chan];
        }
#pragma unroll
        for (int j = 0; j < 8; j++) {
            carry[(cb + j) * NCHAN + chan] = lh;
            lh = laddexp(lh + Cr[j], Vr[j]);
        }
    }
}

__global__ __launch_bounds__(256)
void scan_part3(const u16* __restrict__ kp,
                const float* __restrict__ carry, u16* __restrict__ out) {
    const int tid = threadIdx.x;
    const int hb = blockIdx.x & 7;
    const int c  = (blockIdx.x >> 3) & 63;
    const int b  = blockIdx.x >> 9;
    const int h  = hb * 256 + tid;
    size_t idx = (size_t)(b * Sc + c * CL) * KPW + h;
    size_t odx = (size_t)(b * Sc + c * CL) * Hc + h;
    float lh = carry[c * NCHAN + (b * Hc + h)];
#pragma unroll 4
    for (int t = 0; t < CL; t++) {
        float ct, vt;
        scan_step(bf2f(kp[idx]), bf2f(kp[idx + Hc]), ct, vt);
        lh = laddexp(lh + ct, vt);
        out[odx] = f2bf(__expf(lh));
        idx += KPW;
        odx += Hc;
    }
}

// ---------- casts / weight prep ----------
__global__ __launch_bounds__(256)
void castf2b(const float* __restrict__ in, u16* __restrict__ out, int n) {
    const int i = (blockIdx.x * 256 + threadIdx.x) << 2;
    if (i >= n) return;
    const float4 v = *(const float4*)(in + i);
    u16x4 o;
    o.x = f2bf(v.x); o.y = f2bf(v.y); o.z = f2bf(v.z); o.w = f2bf(v.w);
    *(u16x4*)(out + i) = o;
}

// Fused dual-weight cast + bias concat: dst = [castA | castB] (nPerHalf each),
// bias_dst[0..2048) = bA, [2048..4096) = bB.  grid = 2*nPerHalf/1024.
__global__ __launch_bounds__(256)
void prep2(const float* __restrict__ srcA, const float* __restrict__ srcB,
           const float* __restrict__ bA, const float* __restrict__ bB,
           u16* __restrict__ dst, float* __restrict__ bias_dst, int nPerHalf) {
    const int bid = blockIdx.x, tid = threadIdx.x;
    const int halfBlocks = gridDim.x >> 1;
    const int half = (bid >= halfBlocks) ? 1 : 0;
    const size_t i = ((size_t)(bid - half * halfBlocks) * 256 + tid) * 4;
    const float* src = half ? srcB : srcA;
    const float4 v = *(const float4*)(src + i);
    u16x4 o;
    o.x = f2bf(v.x); o.y = f2bf(v.y); o.z = f2bf(v.z); o.w = f2bf(v.w);
    *(u16x4*)(dst + (size_t)half * nPerHalf + i) = o;
    if (bid < 4) {
        const int j = bid * 1024 + tid * 4;
        const float4 vb = (j < 2048) ? *(const float4*)(bA + j)
                                     : *(const float4*)(bB + (j - 2048));
        *(float4*)(bias_dst + j) = vb;
    }
}

// convW (H,H,3) -> wt (H, 3H): wt[o][k*H + i] = w[o][i][k]  (bf16)
__global__ __launch_bounds__(256)
void conv_tr(const float* __restrict__ w, u16* __restrict__ out) {
    const int idx = blockIdx.x * 256 + threadIdx.x;  // o*H + i
    const float* src = w + (size_t)idx * 3;
    const float a = src[0], b = src[1], c = src[2];
    const int o = idx >> 11, ii = idx & (Hc - 1);
    u16* dst = out + (size_t)o * (3 * Hc) + ii;
    dst[0]        = f2bf(a);
    dst[Hc]       = f2bf(b);
    dst[2 * Hc]   = f2bf(c);
}

// ---------- host ----------
static inline void launch_gemm8(int conv, int epi,
                                const u16* A, const u16* Bw, const float* bias,
                                u16* Cb, float* Cf, const float* resid, u16* xout,
                                int M, int N, int K, int lda,
                                const u16* zero, hipStream_t s) {
    dim3 grid(N / 256, M / 256), blk(512);
    if (conv)
        gemm8<1, 0><<<grid, blk, 0, s>>>(A, Bw, bias, Cb, Cf, resid, xout, M, N, K, lda, zero);
    else if (epi)
        gemm8<0, 1><<<grid, blk, 0, s>>>(A, Bw, bias, Cb, Cf, resid, xout, M, N, K, lda, zero);
    else
        gemm8<0, 0><<<grid, blk, 0, s>>>(A, Bw, bias, Cb, Cf, resid, xout, M, N, K, lda, zero);
}

extern "C" void kernel_launch(void* const* d_in, const int* in_sizes, int n_in,
                              void* d_out, int out_size, void* d_ws, size_t ws_size,
                              hipStream_t stream) {
    (void)in_sizes; (void)n_in; (void)out_size;
    const float* x0    = (const float*)d_in[0];
    const float* Wp1   = (const float*)d_in[1];
    const float* bp1   = (const float*)d_in[2];
    const float* Wp2   = (const float*)d_in[3];
    const float* bp2   = (const float*)d_in[4];
    const float* convW = (const float*)d_in[5];
    const float* convb = (const float*)d_in[6];
    const float* Wz    = (const float*)d_in[7];
    const float* bz    = (const float*)d_in[8];
    const float* Wh    = (const float*)d_in[9];
    const float* bh    = (const float*)d_in[10];
    const float* Wd    = (const float*)d_in[11];
    const float* bd    = (const float*)d_in[12];
    const float* lng   = (const float*)d_in[13];
    const float* lnb   = (const float*)d_in[14];
    float* out = (float*)d_out;

    // ws layout (bytes)
    char* ws = (char*)d_ws;
    u16* wbuf = (u16*)(ws);                       // 24 MB (max weight: conv)
    u16* s1   = (u16*)(ws + 25165824);            // [M][H] bf16
    u16* t1   = (u16*)(ws + 58720256);            // [M][H] bf16
    u16* kp   = (u16*)(ws + 92274688);            // [M][4096] bf16 (k|p fused, 64 MB)
    u16* s2   = kp;                               // non-fused path: reused after scan
    u16* xb   = (u16*)(ws + 159383552);           // [M][D] bf16
    u16* zero = (u16*)(ws + 176160768);           // 1 KiB zero page
    float* scanC = (float*)(ws + 176161792);      // 64*8192 f32
    float* scanV = (float*)(ws + 178258944);
    float* carry = (float*)(ws + 180356096);
    float* bias2 = (float*)(ws + 182453248);      // 4096 f32 concat bias
    u16* P       = (u16*)(ws + 184549376);        // [M][4096] bf16 (proj1|proj2), needs big ws
    const bool FUSEP = ws_size >= 251658240ull;   // P end = 240 MB

    hipMemsetAsync(zero, 0, 1024, stream);
    castf2b<<<dim3((Mc * Dc / 4) / 256), dim3(256), 0, stream>>>(x0, xb, Mc * Dc);

    const size_t wpStride = (size_t)Hc * Dc;      // 2,097,152
    const size_t cvStride = (size_t)Hc * Hc * 3;  // 12,582,912
    const size_t wzStride = (size_t)Hc * Hc;      // 4,194,304
    const size_t wdStride = (size_t)Dc * Hc;      // 2,097,152

    for (int i = 0; i < Lc; ++i) {
        const float* g0 = lng + ((size_t)i * 4 + 0) * Hc; const float* be0 = lnb + ((size_t)i * 4 + 0) * Hc;
        const float* g1 = lng + ((size_t)i * 4 + 1) * Hc; const float* be1 = lnb + ((size_t)i * 4 + 1) * Hc;
        const float* g2 = lng + ((size_t)i * 4 + 2) * Hc; const float* be2 = lnb + ((size_t)i * 4 + 2) * Hc;
        const float* g3 = lng + ((size_t)i * 4 + 3) * Hc; const float* be3 = lnb + ((size_t)i * 4 + 3) * Hc;

        if (FUSEP) {
            // fused proj1|proj2: one N=4096 GEMM sharing the A(xb) fetch
            prep2<<<dim3(2 * (int)(wpStride / 1024)), dim3(256), 0, stream>>>(
                Wp1 + i * wpStride, Wp2 + i * wpStride,
                bp1 + (size_t)i * Hc, bp2 + (size_t)i * Hc, wbuf, bias2, (int)wpStride);
            launch_gemm8(0, 0, xb, wbuf, bias2, P, nullptr, nullptr, nullptr,
                         Mc, KPW, Dc, Dc, zero, stream);
            ln_fuse<<<dim3(Mc), dim3(256), 0, stream>>>(P, KPW, s1, g0, be0, nullptr, 0);
        } else {
            castf2b<<<dim3((int)(wpStride / 4 / 256)), dim3(256), 0, stream>>>(Wp1 + i * wpStride, wbuf, (int)wpStride);
            launch_gemm8(0, 0, xb, wbuf, bp1 + (size_t)i * Hc, t1, nullptr, nullptr, nullptr,
                         Mc, Hc, Dc, Dc, zero, stream);
            ln_fuse<<<dim3(Mc), dim3(256), 0, stream>>>(t1, Hc, s1, g0, be0, nullptr, 0);
        }

        // conv1d (as GEMM over K=3H) + LN1 + SiLU
        conv_tr<<<dim3((Hc * Hc) / 256), dim3(256), 0, stream>>>(convW + i * cvStride, wbuf);
        launch_gemm8(1, 0, s1, wbuf, convb + (size_t)i * Hc, t1, nullptr, nullptr, nullptr,
                     Mc, Hc, 3 * Hc, Hc, zero, stream);
        ln_fuse<<<dim3(Mc), dim3(256), 0, stream>>>(t1, Hc, s1, g1, be1, nullptr, 1);

        // minGRU: fused [k|p] = s1 @ [Wz|Wh]^T + [bz|bh]  (one N=4096 GEMM)
        prep2<<<dim3(2 * (int)(wzStride / 1024)), dim3(256), 0, stream>>>(
            Wz + i * wzStride, Wh + i * wzStride,
            bz + (size_t)i * Hc, bh + (size_t)i * Hc, wbuf, bias2, (int)wzStride);
        launch_gemm8(0, 0, s1, wbuf, bias2, kp, nullptr, nullptr, nullptr,
                     Mc, KPW, Hc, Hc, zero, stream);
        scan_part1<<<dim3(2048), dim3(256), 0, stream>>>(kp, scanC, scanV);
        scan_mid<<<dim3(32), dim3(256), 0, stream>>>(scanC, scanV, carry);
        scan_part3<<<dim3(2048), dim3(256), 0, stream>>>(kp, carry, t1);
        ln_fuse<<<dim3(Mc), dim3(256), 0, stream>>>(t1, Hc, s1, g2, be2, nullptr, 0);

        if (FUSEP) {
            // strand 2 epilogue: LN3+SiLU on P[:,2048:] fused with mul by s1 -> t1
            ln_fuse<<<dim3(Mc), dim3(256), 0, stream>>>(P + Hc, KPW, t1, g3, be3, s1, 1);
            castf2b<<<dim3((int)(wdStride / 4 / 256)), dim3(256), 0, stream>>>(Wd + i * wdStride, wbuf, (int)wdStride);
            launch_gemm8(0, 1, t1, wbuf, bd + (size_t)i * Dc, nullptr, out,
                         (i == 0) ? x0 : out, xb, Mc, Dc, Hc, Hc, zero, stream);
        } else {
            // strand 2: proj2 + LN3 + SiLU, fused multiply by s1 -> s2 (kp region)
            castf2b<<<dim3((int)(wpStride / 4 / 256)), dim3(256), 0, stream>>>(Wp2 + i * wpStride, wbuf, (int)wpStride);
            launch_gemm8(0, 0, xb, wbuf, bp2 + (size_t)i * Hc, t1, nullptr, nullptr, nullptr,
                         Mc, Hc, Dc, Dc, zero, stream);
            ln_fuse<<<dim3(Mc), dim3(256), 0, stream>>>(t1, Hc, s2, g3, be3, s1, 1);
            castf2b<<<dim3((int)(wdStride / 4 / 256)), dim3(256), 0, stream>>>(Wd + i * wdStride, wbuf, (int)wdStride);
            launch_gemm8(0, 1, s2, wbuf, bd + (size_t)i * Dc, nullptr, out,
                         (i == 0) ? x0 : out, xb, Mc, Dc, Hc, Hc, zero, stream);
        }
    }
}

// Round 4
// 2876.611 us; speedup vs baseline: 1.0524x; 1.0162x over previous
//
#include <hip/hip_runtime.h>

// ---------- types / helpers ----------
typedef unsigned short u16;
typedef short  s16x8 __attribute__((ext_vector_type(8)));
typedef float  f32x4 __attribute__((ext_vector_type(4)));
typedef unsigned short u16x4 __attribute__((ext_vector_type(4)));

#define LDS_AS __attribute__((address_space(3)))
#define GLB_AS __attribute__((address_space(1)))

__device__ __forceinline__ float bf2f(u16 x) {
    unsigned u = ((unsigned)x) << 16;
    return __builtin_bit_cast(float, u);
}
__device__ __forceinline__ u16 f2bf(float f) {
    unsigned u = __builtin_bit_cast(unsigned, f);
    return (u16)((u + 0x7FFFu + ((u >> 16) & 1u)) >> 16);  // RNE
}
__device__ __forceinline__ void gload16(const u16* g, u16* l) {
    __builtin_amdgcn_global_load_lds((const GLB_AS unsigned int*)g,
                                     (LDS_AS unsigned int*)l, 16, 0, 0);
}

static constexpr int Lc = 4, Sc = 2048, Dc = 1024, Hc = 2048, Mc = 8192;
static constexpr int CH = 64, CL = 32;  // scan chunks / chunk length (CH*CL == Sc)
static constexpr int NCHAN = 4 * Hc;    // B*H = 8192 channels
static constexpr int KPW = 4096;        // fused dual-output row width

// ============================================================================
// 256x256 8-phase GEMM (T1+T2+T3+T4+T5): C[M,N] = A[M,K] @ Bw[N,K]^T + bias
// BK=64, 512 threads (2Mx4N waves), 128KiB LDS double-buffer, XOR-swizzled
// LDS (pre-swizzled global source + swizzled ds_read), raw s_barrier +
// counted vmcnt(6), XCD-chunked blockIdx swizzle. Compiler-managed lgkmcnt
// (R3 A/B: explicit lgkmcnt(0)+sched_barrier(0) was -5%; reverted).
// REPS: persistent multi-tile — block processes tiles by, by+gridDim.y, ...
// (one launch, B panel stays L2-hot, no inter-round launch gap).
// CONV=1: logical K=3*H over A[M,H] with row shift seg-1 and zero padding.
// ============================================================================
#define BAR() __builtin_amdgcn_s_barrier()
#define VMCNT(n) asm volatile("s_waitcnt vmcnt(" #n ")" ::: "memory")

#define READ_A(d, BUF, MH)                                                     \
    _Pragma("unroll") for (int mf = 0; mf < 4; ++mf) {                         \
        d[mf][0] = *(const s16x8*)(aB0 + (BUF)*16384 + (MH)*4096 + mf*1024);   \
        d[mf][1] = *(const s16x8*)(aB1 + (BUF)*16384 + (MH)*4096 + mf*1024);   \
    }
#define READ_B(BUF, NH)                                                        \
    _Pragma("unroll") for (int jb = 0; jb < 2; ++jb) {                         \
        bq[jb][0] = *(const s16x8*)(bB0 + (BUF)*16384 + (NH)*2048 + jb*1024);  \
        bq[jb][1] = *(const s16x8*)(bB1 + (BUF)*16384 + (NH)*2048 + jb*1024);  \
    }
#define QUAD(a, MH, NH)                                                        \
    _Pragma("unroll") for (int mf = 0; mf < 4; ++mf)                           \
    _Pragma("unroll") for (int jb = 0; jb < 2; ++jb)                           \
    _Pragma("unroll") for (int kk = 0; kk < 2; ++kk)                           \
        acc[(MH)*4 + mf][(NH)*2 + jb] = __builtin_amdgcn_mfma_f32_16x16x32_bf16( \
            a[mf][kk], bq[jb][kk], acc[(MH)*4 + mf][(NH)*2 + jb], 0, 0, 0);

#define STAGE_A(BUF, H, KT) {                                                  \
    if (CONV) {                                                                \
        const int seg_ = ((KT)*64) >> 11;                                      \
        const int kb_  = ((KT)*64) & (Hc - 1);                                 \
        const int r0_  = convRow + (H)*128 + seg_;                             \
        const u16* s0_ = ((unsigned)(r0_ - bb) < (unsigned)Sc)                 \
                             ? A + (size_t)r0_ * lda + kb_ + scol : zerobuf;   \
        const u16* s1_ = ((unsigned)(r0_ + 8 - bb) < (unsigned)Sc)             \
                             ? A + (size_t)(r0_ + 8) * lda + kb_ + scol : zerobuf; \
        gload16(s0_, ldsA + (BUF)*16384 + (H)*8192);                           \
        gload16(s1_, ldsA + (BUF)*16384 + (H)*8192 + 512);                     \
    } else {                                                                   \
        const u16* s_ = srcA + (size_t)((H)*128) * lda + (KT)*64;              \
        gload16(s_,                   ldsA + (BUF)*16384 + (H)*8192);          \
        gload16(s_ + 8*(size_t)lda,   ldsA + (BUF)*16384 + (H)*8192 + 512);    \
    } }
#define STAGE_B(BUF, H, KT) {                                                  \
    const u16* s_ = srcB + (size_t)((H)*128) * K + (KT)*64;                    \
    gload16(s_,                 ldsB + (BUF)*16384 + (H)*8192);                \
    gload16(s_ + 8*(size_t)K,   ldsB + (BUF)*16384 + (H)*8192 + 512);          \
}

template <int CONV, int REPS>
__global__ __launch_bounds__(512, 2)
void gemm8(const u16* __restrict__ A, const u16* __restrict__ Bw,
           const float* __restrict__ bias, u16* __restrict__ Cb,
           int M, int N, int K, int lda, const u16* __restrict__ zerobuf) {
    (void)M;
    __shared__ __align__(16) u16 As[2][256][64];   // 64 KiB
    __shared__ __align__(16) u16 Bs[2][256][64];   // 64 KiB

    const int tid = threadIdx.x;
    const int w = tid >> 6, l = tid & 63;
    const int wm = w & 1, wn = w >> 1;           // 2 x 4 wave grid

    // ---- XCD-chunked bijective swizzle (nwg % 8 == 0 always here) ----
    const unsigned nwg = gridDim.x * gridDim.y;
    unsigned id = blockIdx.x + gridDim.x * blockIdx.y;
    id = (id & 7u) * (nwg >> 3) + (id >> 3);
    const int bx = (int)(id % gridDim.x);
    const int byBase = (int)(id / gridDim.x);
    const int colBase = bx * 256;

    // ---- staging (pre-swizzled source; LDS dest is linear) ----
    const int srow = w * 16 + (l >> 3);          // row within 128-row half
    const int scol = ((l & 7) ^ (l >> 3)) << 3;  // pre-swizzled element col
    const u16* srcB = Bw + (size_t)(colBase + srow) * K + scol;
    u16* const ldsA = &As[0][0][0] + w * 1024;   // + BUF*16384 + H*8192 + j*512
    u16* const ldsB = &Bs[0][0][0] + w * 1024;

    // ---- fragment read bases (swizzled ds_read addresses) ----
    const int r16 = l & 15, slot = l >> 4;
    const int swz = (r16 & 7) << 4;                      // byte swizzle
    const int co0 = (((slot << 4)      ) ^ swz) >> 1;    // u16 units, kk=0
    const int co1 = (((slot << 4) | 64 ) ^ swz) >> 1;    // kk=1
    const u16* aB0 = &As[0][0][0] + (wm * 128 + r16) * 64 + co0;
    const u16* aB1 = &As[0][0][0] + (wm * 128 + r16) * 64 + co1;
    const u16* bB0 = &Bs[0][0][0] + (wn * 64  + r16) * 64 + co0;
    const u16* bB1 = &Bs[0][0][0] + (wn * 64  + r16) * 64 + co1;

    const int coll = colBase + wn * 64 + r16;

    for (int rep = 0; rep < REPS; ++rep) {
        const int rowBase = (byBase + rep * gridDim.y) * 256;
        const u16* srcA = A + (size_t)(rowBase + srow) * lda + scol;  // non-conv
        const int bb = rowBase & ~(Sc - 1);          // batch start (conv)
        const int convRow = rowBase + srow - 1;      // + H*128 + seg

        f32x4 acc[8][4];
#pragma unroll
        for (int m = 0; m < 8; ++m)
#pragma unroll
            for (int n = 0; n < 4; ++n)
#pragma unroll
                for (int r = 0; r < 4; ++r) acc[m][n][r] = 0.f;

        s16x8 a0[4][2], a1[4][2], bq[2][2];

        // ---- prologue: tile0 complete + tile1 {A0,A1,B0}; 3 half-tiles in flight
        // (for rep>0 the VMCNTs also drain the previous epilogue's stores — safe)
        STAGE_A(0, 0, 0); STAGE_A(0, 1, 0); STAGE_B(0, 0, 0); STAGE_B(0, 1, 0);
        VMCNT(4);
        STAGE_A(1, 0, 1); STAGE_A(1, 1, 1); STAGE_B(1, 0, 1);
        VMCNT(6);
        BAR();

        const int NI = K >> 7;                  // 2 K-tiles per iteration
        for (int i = 0; i < NI; ++i) {
            const int t1 = 2 * i + 1, t2 = 2 * i + 2, t3 = 2 * i + 3;
            const bool more = (i + 1 < NI);
            // -- phase 1: tile even (buf0), quad (0,0); stage t1.B1 -> buf1
            READ_A(a0, 0, 0); READ_B(0, 0);
            STAGE_B(1, 1, t1);
            BAR();
            __builtin_amdgcn_s_setprio(1); QUAD(a0, 0, 0); __builtin_amdgcn_s_setprio(0);
            BAR();
            // -- phase 2: quad (1,0)
            READ_A(a1, 0, 1);
            BAR();
            __builtin_amdgcn_s_setprio(1); QUAD(a1, 1, 0); __builtin_amdgcn_s_setprio(0);
            BAR();
            // -- phase 3: quad (0,1); stage t2.A0,t2.A1 -> buf0 (A fully read)
            READ_B(0, 1);
            if (more) { STAGE_A(0, 0, t2); STAGE_A(0, 1, t2); }
            BAR();
            __builtin_amdgcn_s_setprio(1); QUAD(a0, 0, 1); __builtin_amdgcn_s_setprio(0);
            BAR();
            // -- phase 4: quad (1,1); stage t2.B0; tile-boundary counted wait
            if (more) STAGE_B(0, 0, t2);
            BAR();
            __builtin_amdgcn_s_setprio(1); QUAD(a1, 1, 1); __builtin_amdgcn_s_setprio(0);
            if (more) { VMCNT(6); } else { VMCNT(0); }
            BAR();
            // -- phase 5: tile odd (buf1), quad (0,0); stage t2.B1
            READ_A(a0, 1, 0); READ_B(1, 0);
            if (more) STAGE_B(0, 1, t2);
            BAR();
            __builtin_amdgcn_s_setprio(1); QUAD(a0, 0, 0); __builtin_amdgcn_s_setprio(0);
            BAR();
            // -- phase 6: quad (1,0)
            READ_A(a1, 1, 1);
            BAR();
            __builtin_amdgcn_s_setprio(1); QUAD(a1, 1, 0); __builtin_amdgcn_s_setprio(0);
            BAR();
            // -- phase 7: quad (0,1); stage t3.A0,t3.A1 -> buf1
            READ_B(1, 1);
            if (more) { STAGE_A(1, 0, t3); STAGE_A(1, 1, t3); }
            BAR();
            __builtin_amdgcn_s_setprio(1); QUAD(a0, 0, 1); __builtin_amdgcn_s_setprio(0);
            BAR();
            // -- phase 8: quad (1,1); stage t3.B0; counted wait for next iter
            if (more) STAGE_B(1, 0, t3);
            BAR();
            __builtin_amdgcn_s_setprio(1); QUAD(a1, 1, 1); __builtin_amdgcn_s_setprio(0);
            if (more) VMCNT(6);
            BAR();
        }

        // ---- epilogue ----
        const int row00 = rowBase + wm * 128 + slot * 4;
#pragma unroll
        for (int m8 = 0; m8 < 8; ++m8) {
#pragma unroll
            for (int n4 = 0; n4 < 4; ++n4) {
                const int col = coll + n4 * 16;
                const float bv = bias[col];
                const int row0 = row00 + m8 * 16;
#pragma unroll
                for (int r = 0; r < 4; ++r)
                    Cb[(size_t)(row0 + r) * N + col] = f2bf(acc[m8][n4][r] + bv);
            }
        }
    }
}

// ---------- legacy 128x128 GEMM (down-proj EPI path: full-chip 512-block grid) ----------
template <int CONV, int EPI>
__global__ __launch_bounds__(256)
void gemm_bt(const u16* __restrict__ A, const u16* __restrict__ Bw,
             const float* __restrict__ bias,
             u16* __restrict__ Cb, float* __restrict__ Cf,
             const float* __restrict__ resid, u16* __restrict__ xout,
             int M, int N, int K, int lda, const u16* __restrict__ zerobuf) {
    __shared__ __align__(16) u16 As[128 * 32];
    __shared__ __align__(16) u16 Bs[128 * 32];
    const int tid  = threadIdx.x;
    const int wave = tid >> 6, lane = tid & 63;
    const int rowBase = blockIdx.y * 128;
    const int colBase = blockIdx.x * 128;
    const int srow = tid >> 2;          // staging row within 0..63
    const int scol = (tid & 3) << 3;    // staging col (elements)

    u16* ldsA0 = As + wave * 512;
    u16* ldsA1 = As + 2048 + wave * 512;
    u16* ldsB0 = Bs + wave * 512;
    u16* ldsB1 = Bs + 2048 + wave * 512;

    const u16* bpt0 = Bw + (size_t)(colBase + srow) * K + scol;
    const u16* bpt1 = Bw + (size_t)(colBase + 64 + srow) * K + scol;
    const int arow0 = rowBase + srow;
    const int arow1 = arow0 + 64;
    const u16* ap0 = A + (size_t)arow0 * lda + scol;
    const u16* ap1 = A + (size_t)arow1 * lda + scol;

    const int wm = wave & 1, wn = wave >> 1;
    const int mB = wm * 64, nB = wn * 64;
    const int quad = lane >> 4, l16 = lane & 15;

    f32x4 acc[4][4];
#pragma unroll
    for (int a = 0; a < 4; a++)
#pragma unroll
        for (int b = 0; b < 4; b++)
#pragma unroll
            for (int r = 0; r < 4; r++) acc[a][b][r] = 0.f;

    for (int k0 = 0; k0 < K; k0 += 32) {
        if (CONV) {
            const int seg = k0 >> 11;                 // /H
            const int kk  = (k0 & (Hc - 1)) + scol;
            const int bbb = rowBase & ~(Sc - 1);      // batch start (flat row)
            const int r0  = arow0 + seg - 1;
            const int r1  = arow1 + seg - 1;
            const u16* g0 = ((unsigned)(r0 - bbb) < (unsigned)Sc) ? A + (size_t)r0 * lda + kk : zerobuf;
            const u16* g1 = ((unsigned)(r1 - bbb) < (unsigned)Sc) ? A + (size_t)r1 * lda + kk : zerobuf;
            gload16(g0, ldsA0);
            gload16(g1, ldsA1);
        } else {
            gload16(ap0 + k0, ldsA0);
            gload16(ap1 + k0, ldsA1);
        }
        gload16(bpt0 + k0, ldsB0);
        gload16(bpt1 + k0, ldsB1);
        __syncthreads();

        s16x8 af[4], bfr[4];
#pragma unroll
        for (int t = 0; t < 4; t++)
            af[t] = *(const s16x8*)(As + (mB + t * 16 + l16) * 32 + (quad << 3));
#pragma unroll
        for (int t = 0; t < 4; t++)
            bfr[t] = *(const s16x8*)(Bs + (nB + t * 16 + l16) * 32 + (quad << 3));
#pragma unroll
        for (int mt = 0; mt < 4; mt++)
#pragma unroll
            for (int nt = 0; nt < 4; nt++)
                acc[mt][nt] = __builtin_amdgcn_mfma_f32_16x16x32_bf16(af[mt], bfr[nt], acc[mt][nt], 0, 0, 0);
        __syncthreads();
    }

#pragma unroll
    for (int mt = 0; mt < 4; mt++) {
#pragma unroll
        for (int nt = 0; nt < 4; nt++) {
            const int col  = colBase + nB + nt * 16 + l16;
            const int row0 = rowBase + mB + mt * 16 + (quad << 2);
            const float bv = bias[col];
#pragma unroll
            for (int r = 0; r < 4; r++) {
                const size_t idx = (size_t)(row0 + r) * N + col;
                float v = acc[mt][nt][r] + bv;
                if (EPI == 0) {
                    Cb[idx] = f2bf(v);
                } else {
                    v += resid[idx];
                    Cf[idx]   = v;
                    xout[idx] = f2bf(v);
                }
            }
        }
    }
}

// ---------- LayerNorm over H=2048 (+ optional SiLU, + optional elementwise mul) ----------
// instride: row stride of `in` (Hc normally; KPW for fused dual-output buffers)
__global__ __launch_bounds__(256)
void ln_fuse(const u16* __restrict__ in, int instride, u16* __restrict__ out,
             const float* __restrict__ g, const float* __restrict__ b,
             const u16* __restrict__ mul, int do_silu) {
    __shared__ float sred[4], qred[4];
    const int row = blockIdx.x, tid = threadIdx.x;
    const int lane = tid & 63, wave = tid >> 6;
    const size_t ibase = (size_t)row * instride + tid * 8;
    const size_t obase = (size_t)row * Hc + tid * 8;

    s16x8 v8 = *(const s16x8*)(in + ibase);
    float x[8];
#pragma unroll
    for (int j = 0; j < 8; j++) x[j] = bf2f((u16)v8[j]);
    float s = 0.f, q = 0.f;
#pragma unroll
    for (int j = 0; j < 8; j++) { s += x[j]; q += x[j] * x[j]; }
#pragma unroll
    for (int off = 32; off > 0; off >>= 1) {
        s += __shfl_down(s, off);
        q += __shfl_down(q, off);
    }
    if (lane == 0) { sred[wave] = s; qred[wave] = q; }
    __syncthreads();
    const float St = sred[0] + sred[1] + sred[2] + sred[3];
    const float Qt = qred[0] + qred[1] + qred[2] + qred[3];
    const float mean = St * (1.0f / Hc);
    const float var  = Qt * (1.0f / Hc) - mean * mean;
    const float rs   = rsqrtf(var + 1e-5f);

    const int c = tid * 8;
    const float4 g0 = *(const float4*)(g + c), g1 = *(const float4*)(g + c + 4);
    const float4 b0 = *(const float4*)(b + c), b1 = *(const float4*)(b + c + 4);
    const float gg[8] = {g0.x, g0.y, g0.z, g0.w, g1.x, g1.y, g1.z, g1.w};
    const float bb[8] = {b0.x, b0.y, b0.z, b0.w, b1.x, b1.y, b1.z, b1.w};
    s16x8 m8;
    if (mul) m8 = *(const s16x8*)(mul + obase);
    s16x8 o8;
#pragma unroll
    for (int j = 0; j < 8; j++) {
        float y = (x[j] - mean) * rs * gg[j] + bb[j];
        if (do_silu) y = y / (1.0f + __expf(-y));
        if (mul) y *= bf2f((u16)m8[j]);
        o8[j] = (short)f2bf(y);
    }
    *(s16x8*)(out + obase) = o8;
}

// ---------- minGRU log-space CHUNKED parallel scan (fused k|p input, width 4096) ----------
__device__ __forceinline__ void scan_step(float k, float p, float& ct, float& vt) {
    const float l1p = __logf(1.f + __expf(-fabsf(k)));
    ct = -(fmaxf(k, 0.f) + l1p);                      // -softplus(k)
    const float lg = (p >= 0.f) ? __logf(p + 0.5f)
                                : -(fmaxf(-p, 0.f) + __logf(1.f + __expf(-fabsf(p))));
    vt = -(fmaxf(-k, 0.f) + l1p) + lg;                // -softplus(-k) + log_g
}
__device__ __forceinline__ float laddexp(float a, float b) {
    const float m = fmaxf(a, b);
    return m + __logf(1.f + __expf(-fabsf(a - b)));
}

__global__ __launch_bounds__(256)
void scan_part1(const u16* __restrict__ kp,
                float* __restrict__ Cc, float* __restrict__ Vv) {
    const int tid = threadIdx.x;
    const int hb = blockIdx.x & 7;          // H/256 = 8
    const int c  = (blockIdx.x >> 3) & 63;  // chunk
    const int b  = blockIdx.x >> 9;         // batch
    const int h  = hb * 256 + tid;
    size_t idx = (size_t)(b * Sc + c * CL) * KPW + h;
    float C = 0.f, V = -1e30f;
#pragma unroll 4
    for (int t = 0; t < CL; t++) {
        float ct, vt;
        scan_step(bf2f(kp[idx]), bf2f(kp[idx + Hc]), ct, vt);
        V = laddexp(V + ct, vt);
        C += ct;
        idx += KPW;
    }
    const int chan = b * Hc + h;
    Cc[c * NCHAN + chan] = C;
    Vv[c * NCHAN + chan] = V;
}

// batched-prefetch serial chunk-scan: 8 (C,V) pairs in flight per thread
__global__ __launch_bounds__(256)
void scan_mid(const float* __restrict__ Cc, const float* __restrict__ Vv,
              float* __restrict__ carry) {
    const int chan = blockIdx.x * 256 + threadIdx.x;  // 0..8191
    float lh = -0.69314718f;                          // log 0.5
    for (int cb = 0; cb < CH; cb += 8) {
        float Cr[8], Vr[8];
#pragma unroll
        for (int j = 0; j < 8; j++) {
            Cr[j] = Cc[(cb + j) * NCHAN + chan];
            Vr[j] = Vv[(cb + j) * NCHAN + chan];
        }
#pragma unroll
        for (int j = 0; j < 8; j++) {
            carry[(cb + j) * NCHAN + chan] = lh;
            lh = laddexp(lh + Cr[j], Vr[j]);
        }
    }
}

__global__ __launch_bounds__(256)
void scan_part3(const u16* __restrict__ kp,
                const float* __restrict__ carry, u16* __restrict__ out) {
    const int tid = threadIdx.x;
    const int hb = blockIdx.x & 7;
    const int c  = (blockIdx.x >> 3) & 63;
    const int b  = blockIdx.x >> 9;
    const int h  = hb * 256 + tid;
    size_t idx = (size_t)(b * Sc + c * CL) * KPW + h;
    size_t odx = (size_t)(b * Sc + c * CL) * Hc + h;
    float lh = carry[c * NCHAN + (b * Hc + h)];
#pragma unroll 4
    for (int t = 0; t < CL; t++) {
        float ct, vt;
        scan_step(bf2f(kp[idx]), bf2f(kp[idx + Hc]), ct, vt);
        lh = laddexp(lh + ct, vt);
        out[odx] = f2bf(__expf(lh));
        idx += KPW;
        odx += Hc;
    }
}

// ---------- casts / weight prep ----------
__global__ __launch_bounds__(256)
void castf2b(const float* __restrict__ in, u16* __restrict__ out, int n) {
    const int i = (blockIdx.x * 256 + threadIdx.x) << 2;
    if (i >= n) return;
    const float4 v = *(const float4*)(in + i);
    u16x4 o;
    o.x = f2bf(v.x); o.y = f2bf(v.y); o.z = f2bf(v.z); o.w = f2bf(v.w);
    *(u16x4*)(out + i) = o;
}

// Fused dual-weight cast + bias concat: dst = [castA | castB] (nPerHalf each),
// bias_dst[0..2048) = bA, [2048..4096) = bB.  grid = 2*nPerHalf/1024.
__global__ __launch_bounds__(256)
void prep2(const float* __restrict__ srcA, const float* __restrict__ srcB,
           const float* __restrict__ bA, const float* __restrict__ bB,
           u16* __restrict__ dst, float* __restrict__ bias_dst, int nPerHalf) {
    const int bid = blockIdx.x, tid = threadIdx.x;
    const int halfBlocks = gridDim.x >> 1;
    const int half = (bid >= halfBlocks) ? 1 : 0;
    const size_t i = ((size_t)(bid - half * halfBlocks) * 256 + tid) * 4;
    const float* src = half ? srcB : srcA;
    const float4 v = *(const float4*)(src + i);
    u16x4 o;
    o.x = f2bf(v.x); o.y = f2bf(v.y); o.z = f2bf(v.z); o.w = f2bf(v.w);
    *(u16x4*)(dst + (size_t)half * nPerHalf + i) = o;
    if (bid < 4) {
        const int j = bid * 1024 + tid * 4;
        const float4 vb = (j < 2048) ? *(const float4*)(bA + j)
                                     : *(const float4*)(bB + (j - 2048));
        *(float4*)(bias_dst + j) = vb;
    }
}

// convW (H,H,3) -> wt (H, 3H): wt[o][k*H + i] = w[o][i][k]  (bf16)
__global__ __launch_bounds__(256)
void conv_tr(const float* __restrict__ w, u16* __restrict__ out) {
    const int idx = blockIdx.x * 256 + threadIdx.x;  // o*H + i
    const float* src = w + (size_t)idx * 3;
    const float a = src[0], b = src[1], c = src[2];
    const int o = idx >> 11, ii = idx & (Hc - 1);
    u16* dst = out + (size_t)o * (3 * Hc) + ii;
    dst[0]        = f2bf(a);
    dst[Hc]       = f2bf(b);
    dst[2 * Hc]   = f2bf(c);
}

// ---------- host ----------
extern "C" void kernel_launch(void* const* d_in, const int* in_sizes, int n_in,
                              void* d_out, int out_size, void* d_ws, size_t ws_size,
                              hipStream_t stream) {
    (void)in_sizes; (void)n_in; (void)out_size;
    const float* x0    = (const float*)d_in[0];
    const float* Wp1   = (const float*)d_in[1];
    const float* bp1   = (const float*)d_in[2];
    const float* Wp2   = (const float*)d_in[3];
    const float* bp2   = (const float*)d_in[4];
    const float* convW = (const float*)d_in[5];
    const float* convb = (const float*)d_in[6];
    const float* Wz    = (const float*)d_in[7];
    const float* bz    = (const float*)d_in[8];
    const float* Wh    = (const float*)d_in[9];
    const float* bh    = (const float*)d_in[10];
    const float* Wd    = (const float*)d_in[11];
    const float* bd    = (const float*)d_in[12];
    const float* lng   = (const float*)d_in[13];
    const float* lnb   = (const float*)d_in[14];
    float* out = (float*)d_out;

    // ws layout (bytes)
    char* ws = (char*)d_ws;
    u16* wbuf = (u16*)(ws);                       // 24 MB (max weight: conv)
    u16* s1   = (u16*)(ws + 25165824);            // [M][H] bf16
    u16* t1   = (u16*)(ws + 58720256);            // [M][H] bf16
    u16* kp   = (u16*)(ws + 92274688);            // [M][4096] bf16 (k|p fused, 64 MB)
    u16* s2   = kp;                               // non-fused path: reused after scan
    u16* xb   = (u16*)(ws + 159383552);           // [M][D] bf16
    u16* zero = (u16*)(ws + 176160768);           // 1 KiB zero page
    float* scanC = (float*)(ws + 176161792);      // 64*8192 f32
    float* scanV = (float*)(ws + 178258944);
    float* carry = (float*)(ws + 180356096);
    float* bias2 = (float*)(ws + 182453248);      // 4096 f32 concat bias
    u16* P       = (u16*)(ws + 184549376);        // [M][4096] bf16 (proj1|proj2), needs big ws
    const bool FUSEP = ws_size >= 251658240ull;   // P end = 240 MB

    hipMemsetAsync(zero, 0, 1024, stream);
    castf2b<<<dim3((Mc * Dc / 4) / 256), dim3(256), 0, stream>>>(x0, xb, Mc * Dc);

    const size_t wpStride = (size_t)Hc * Dc;      // 2,097,152
    const size_t cvStride = (size_t)Hc * Hc * 3;  // 12,582,912
    const size_t wzStride = (size_t)Hc * Hc;      // 4,194,304
    const size_t wdStride = (size_t)Dc * Hc;      // 2,097,152

    for (int i = 0; i < Lc; ++i) {
        const float* g0 = lng + ((size_t)i * 4 + 0) * Hc; const float* be0 = lnb + ((size_t)i * 4 + 0) * Hc;
        const float* g1 = lng + ((size_t)i * 4 + 1) * Hc; const float* be1 = lnb + ((size_t)i * 4 + 1) * Hc;
        const float* g2 = lng + ((size_t)i * 4 + 2) * Hc; const float* be2 = lnb + ((size_t)i * 4 + 2) * Hc;
        const float* g3 = lng + ((size_t)i * 4 + 3) * Hc; const float* be3 = lnb + ((size_t)i * 4 + 3) * Hc;

        if (FUSEP) {
            // fused proj1|proj2: one N=4096 GEMM sharing the A(xb) fetch
            prep2<<<dim3(2 * (int)(wpStride / 1024)), dim3(256), 0, stream>>>(
                Wp1 + i * wpStride, Wp2 + i * wpStride,
                bp1 + (size_t)i * Hc, bp2 + (size_t)i * Hc, wbuf, bias2, (int)wpStride);
            gemm8<0, 2><<<dim3(KPW / 256, Mc / 512), dim3(512), 0, stream>>>(
                xb, wbuf, bias2, P, Mc, KPW, Dc, Dc, zero);
            ln_fuse<<<dim3(Mc), dim3(256), 0, stream>>>(P, KPW, s1, g0, be0, nullptr, 0);
        } else {
            castf2b<<<dim3((int)(wpStride / 4 / 256)), dim3(256), 0, stream>>>(Wp1 + i * wpStride, wbuf, (int)wpStride);
            gemm8<0, 2><<<dim3(Hc / 256, Mc / 512), dim3(512), 0, stream>>>(
                xb, wbuf, bp1 + (size_t)i * Hc, t1, Mc, Hc, Dc, Dc, zero);
            ln_fuse<<<dim3(Mc), dim3(256), 0, stream>>>(t1, Hc, s1, g0, be0, nullptr, 0);
        }

        // conv1d (as GEMM over K=3H) + LN1 + SiLU
        conv_tr<<<dim3((Hc * Hc) / 256), dim3(256), 0, stream>>>(convW + i * cvStride, wbuf);
        gemm8<1, 1><<<dim3(Hc / 256, Mc / 256), dim3(512), 0, stream>>>(
            s1, wbuf, convb + (size_t)i * Hc, t1, Mc, Hc, 3 * Hc, Hc, zero);
        ln_fuse<<<dim3(Mc), dim3(256), 0, stream>>>(t1, Hc, s1, g1, be1, nullptr, 1);

        // minGRU: fused [k|p] = s1 @ [Wz|Wh]^T + [bz|bh]  (one N=4096 GEMM, REPS=2)
        prep2<<<dim3(2 * (int)(wzStride / 1024)), dim3(256), 0, stream>>>(
            Wz + i * wzStride, Wh + i * wzStride,
            bz + (size_t)i * Hc, bh + (size_t)i * Hc, wbuf, bias2, (int)wzStride);
        gemm8<0, 2><<<dim3(KPW / 256, Mc / 512), dim3(512), 0, stream>>>(
            s1, wbuf, bias2, kp, Mc, KPW, Hc, Hc, zero);
        scan_part1<<<dim3(2048), dim3(256), 0, stream>>>(kp, scanC, scanV);
        scan_mid<<<dim3(32), dim3(256), 0, stream>>>(scanC, scanV, carry);
        scan_part3<<<dim3(2048), dim3(256), 0, stream>>>(kp, carry, t1);
        ln_fuse<<<dim3(Mc), dim3(256), 0, stream>>>(t1, Hc, s1, g2, be2, nullptr, 0);

        if (FUSEP) {
            // strand 2 epilogue: LN3+SiLU on P[:,2048:] fused with mul by s1 -> t1
            ln_fuse<<<dim3(Mc), dim3(256), 0, stream>>>(P + Hc, KPW, t1, g3, be3, s1, 1);
            castf2b<<<dim3((int)(wdStride / 4 / 256)), dim3(256), 0, stream>>>(Wd + i * wdStride, wbuf, (int)wdStride);
            gemm_bt<0, 1><<<dim3(Dc / 128, Mc / 128), dim3(256), 0, stream>>>(
                t1, wbuf, bd + (size_t)i * Dc, nullptr, out,
                (i == 0) ? x0 : out, xb, Mc, Dc, Hc, Hc, zero);
        } else {
            // strand 2: proj2 + LN3 + SiLU, fused multiply by s1 -> s2 (kp region)
            castf2b<<<dim3((int)(wpStride / 4 / 256)), dim3(256), 0, stream>>>(Wp2 + i * wpStride, wbuf, (int)wpStride);
            gemm8<0, 2><<<dim3(Hc / 256, Mc / 512), dim3(512), 0, stream>>>(
                xb, wbuf, bp2 + (size_t)i * Hc, t1, Mc, Hc, Dc, Dc, zero);
            ln_fuse<<<dim3(Mc), dim3(256), 0, stream>>>(t1, Hc, s2, g3, be3, s1, 1);
            castf2b<<<dim3((int)(wdStride / 4 / 256)), dim3(256), 0, stream>>>(Wd + i * wdStride, wbuf, (int)wdStride);
            gemm_bt<0, 1><<<dim3(Dc / 128, Mc / 128), dim3(256), 0, stream>>>(
                s2, wbuf, bd + (size_t)i * Dc, nullptr, out,
                (i == 0) ? x0 : out, xb, Mc, Dc, Hc, Hc, zero);
        }
    }
}